// Round 4
// baseline (787.156 us; speedup 1.0000x reference)
//
#include <hip/hip_runtime.h>

#define N_NODES   50000
#define N_EDGES   600000
#define IN_CH     300
#define HID       128
#define N_CLASSES 2
#define N_GRAPHS  128
#define BN_EPS    1e-5f

typedef __attribute__((ext_vector_type(8))) short bf8_t;   // 8 bf16 (4 VGPRs)
typedef __attribute__((ext_vector_type(4))) float f4_t;    // MFMA acc

// bf16 round-to-nearest-even helpers
__device__ __forceinline__ unsigned short f2bf(float x) {
    union { float f; unsigned u; } q; q.f = x;
    unsigned r = q.u + 0x7fffu + ((q.u >> 16) & 1u);
    return (unsigned short)(r >> 16);
}
__device__ __forceinline__ float bf2f(unsigned short h) {
    union { float f; unsigned u; } q; q.u = ((unsigned)h) << 16; return q.f;
}

// ---------------------------------------------------------------------------
// CSR construction: degree count -> scan -> bucket fill
// ---------------------------------------------------------------------------
__global__ __launch_bounds__(256) void deg_kernel(const int* __restrict__ dst,
                                                  int* __restrict__ ideg) {
    int e = blockIdx.x * 256 + threadIdx.x;
    if (e < N_EDGES) atomicAdd(&ideg[dst[e]], 1);
}

__global__ __launch_bounds__(256) void invdeg_kernel(const int* __restrict__ ideg,
                                                     float* __restrict__ invdeg) {
    int i = blockIdx.x * 256 + threadIdx.x;
    if (i < N_NODES) invdeg[i] = 1.0f / fmaxf((float)ideg[i], 1.0f);
}

#define SCAN_T 1024
__global__ __launch_bounds__(SCAN_T) void scan_kernel(const int* __restrict__ ideg,
                                                      int* __restrict__ row_start) {
    __shared__ int part[SCAN_T];
    int t = threadIdx.x;
    const int chunk = (N_NODES + SCAN_T - 1) / SCAN_T;
    int b = t * chunk;
    int e = min(b + chunk, N_NODES);
    int s = 0;
    for (int i = b; i < e; ++i) s += ideg[i];
    part[t] = s;
    __syncthreads();
    for (int off = 1; off < SCAN_T; off <<= 1) {
        int v = (t >= off) ? part[t - off] : 0;
        __syncthreads();
        part[t] += v;
        __syncthreads();
    }
    int run = (t == 0) ? 0 : part[t - 1];
    for (int i = b; i < e; ++i) {
        row_start[i] = run;
        run += ideg[i];
    }
    if (t == SCAN_T - 1) row_start[N_NODES] = run;
}

__global__ __launch_bounds__(256) void fill_kernel(const int* __restrict__ src,
                                                   const int* __restrict__ dst,
                                                   const int* __restrict__ row_start,
                                                   int* __restrict__ cursor,
                                                   int* __restrict__ csr_src) {
    int e = blockIdx.x * 256 + threadIdx.x;
    if (e >= N_EDGES) return;
    int d = dst[e];
    int pos = row_start[d] + atomicAdd(&cursor[d], 1);
    csr_src[pos] = src[e];
}

// ---------------------------------------------------------------------------
// x -> split bf16 hi/lo planes (M x 320, zero-padded cols 300..319)
// one thread per 4 columns
// ---------------------------------------------------------------------------
#define KP1 320
__global__ __launch_bounds__(256) void prep_x(const float* __restrict__ x,
                                              unsigned short* __restrict__ Ahi,
                                              unsigned short* __restrict__ Alo) {
    int idx = blockIdx.x * 256 + threadIdx.x;  // over N_NODES * 80
    if (idx >= N_NODES * (KP1 / 4)) return;
    int row = idx / (KP1 / 4);
    int c4  = (idx - row * (KP1 / 4)) * 4;
    float4 v = make_float4(0.f, 0.f, 0.f, 0.f);
    if (c4 < IN_CH) v = *(const float4*)&x[(long)row * IN_CH + c4];  // 300 % 4 == 0
    ushort4 h, l;
    h.x = f2bf(v.x); l.x = f2bf(v.x - bf2f(h.x));
    h.y = f2bf(v.y); l.y = f2bf(v.y - bf2f(h.y));
    h.z = f2bf(v.z); l.z = f2bf(v.z - bf2f(h.z));
    h.w = f2bf(v.w); l.w = f2bf(v.w - bf2f(h.w));
    *(ushort4*)&Ahi[(long)row * KP1 + c4] = h;
    *(ushort4*)&Alo[(long)row * KP1 + c4] = l;
}

// ---------------------------------------------------------------------------
// weight prep: BT[n][k] (256 x Kp, bf16 hi/lo, zero-padded k>=K)
// ---------------------------------------------------------------------------
__global__ __launch_bounds__(256) void prep_w(const float* __restrict__ Wl,
                                              const float* __restrict__ Wr,
                                              int K, int Kp,
                                              unsigned short* __restrict__ Bhi,
                                              unsigned short* __restrict__ Blo) {
    int idx = blockIdx.x * 256 + threadIdx.x;
    if (idx >= 256 * Kp) return;
    int n = idx / Kp;
    int k = idx - n * Kp;
    float v = 0.f;
    if (k < K) v = (n < 128) ? Wl[k * 128 + n] : Wr[k * 128 + (n - 128)];
    unsigned short h = f2bf(v);
    unsigned short l = f2bf(v - bf2f(h));
    Bhi[idx] = h;
    Blo[idx] = l;
}

// ---------------------------------------------------------------------------
// split-bf16 MFMA GEMM:  C0 = A@Wl ,  C1 = A@Wr + bias   (N = 128+128)
// A pre-split: Ahi/Alo M x Kp bf16. B pre-split: 256 x Kp bf16.
// block = 4 waves; block tile 64(M) x 256(N); wave tile 64x64 = 4x4 MFMA 16x16x32.
// fp32 via Dekker: ah*bh + al*bh + ah*bl.
// ---------------------------------------------------------------------------
__global__ __launch_bounds__(256) void gemm_mfma(const unsigned short* __restrict__ Ahi,
                                                 const unsigned short* __restrict__ Alo,
                                                 int M, int Kp,
                                                 const unsigned short* __restrict__ Bhi,
                                                 const unsigned short* __restrict__ Blo,
                                                 const float* __restrict__ bias,
                                                 float* __restrict__ C0,
                                                 float* __restrict__ C1) {
    const int lane = threadIdx.x & 63;
    const int wave = threadIdx.x >> 6;
    const int l16  = lane & 15;
    const int quad = lane >> 4;
    const long m0  = (long)blockIdx.x * 64;
    const int  n0  = wave * 64;

    f4_t acc[4][4];
#pragma unroll
    for (int mt = 0; mt < 4; ++mt)
#pragma unroll
        for (int nt = 0; nt < 4; ++nt) acc[mt][nt] = (f4_t){0.f, 0.f, 0.f, 0.f};

    long arow[4];
#pragma unroll
    for (int mt = 0; mt < 4; ++mt) {
        long r = m0 + mt * 16 + l16;
        arow[mt] = (r < M) ? r : (long)(M - 1);  // clamp; clamped rows never stored
    }
    long brow[4];
#pragma unroll
    for (int nt = 0; nt < 4; ++nt) brow[nt] = (long)(n0 + nt * 16 + l16);

    for (int k0 = 0; k0 < Kp; k0 += 32) {
        bf8_t ah[4], al[4];
#pragma unroll
        for (int mt = 0; mt < 4; ++mt) {
            const unsigned short* p = Ahi + arow[mt] * Kp + k0 + quad * 8;
            const unsigned short* q = Alo + arow[mt] * Kp + k0 + quad * 8;
            ah[mt] = *(const bf8_t*)p;
            al[mt] = *(const bf8_t*)q;
        }
#pragma unroll
        for (int nt = 0; nt < 4; ++nt) {
            const unsigned short* pb = Bhi + brow[nt] * Kp + k0 + quad * 8;
            const unsigned short* ql = Blo + brow[nt] * Kp + k0 + quad * 8;
            bf8_t bh = *(const bf8_t*)pb;
            bf8_t bl = *(const bf8_t*)ql;
#pragma unroll
            for (int mt = 0; mt < 4; ++mt) {
                acc[mt][nt] = __builtin_amdgcn_mfma_f32_16x16x32_bf16(ah[mt], bh, acc[mt][nt], 0, 0, 0);
                acc[mt][nt] = __builtin_amdgcn_mfma_f32_16x16x32_bf16(al[mt], bh, acc[mt][nt], 0, 0, 0);
                acc[mt][nt] = __builtin_amdgcn_mfma_f32_16x16x32_bf16(ah[mt], bl, acc[mt][nt], 0, 0, 0);
            }
        }
    }

    // epilogue: wave-uniform half selection (n0<128 -> C0, else C1 + bias)
    const bool left = (n0 < 128);
    float* __restrict__ Cb = left ? C0 : C1;
    float badd[4];
    int   ncol[4];
#pragma unroll
    for (int nt = 0; nt < 4; ++nt) {
        int ng = n0 + nt * 16 + l16;
        ncol[nt] = left ? ng : (ng - 128);
        badd[nt] = left ? 0.f : bias[ng - 128];
    }
#pragma unroll
    for (int mt = 0; mt < 4; ++mt) {
#pragma unroll
        for (int r = 0; r < 4; ++r) {
            long row = m0 + mt * 16 + quad * 4 + r;
            if (row < M) {
#pragma unroll
                for (int nt = 0; nt < 4; ++nt)
                    Cb[row * 128 + ncol[nt]] = acc[mt][nt][r] + badd[nt];
            }
        }
    }
}

// ---------------------------------------------------------------------------
// CSR gather: out[n] += invdeg[n] * sum_{j in adj(n)} Pl[csr_src[j]]
// 32 lanes/node (float4/lane), 8 nodes/block, 4-edge unroll for MLP.
// ---------------------------------------------------------------------------
__global__ __launch_bounds__(256) void gather_agg(const float* __restrict__ Pl,
                                                  const int* __restrict__ row_start,
                                                  const int* __restrict__ csr_src,
                                                  const float* __restrict__ invdeg,
                                                  float* __restrict__ out) {
    int slot = threadIdx.x >> 5;
    int lane = threadIdx.x & 31;
    int node = blockIdx.x * 8 + slot;
    if (node >= N_NODES) return;
    int beg = row_start[node];
    int end = row_start[node + 1];
    const float* base = Pl + lane * 4;
    float sx = 0.f, sy = 0.f, sz = 0.f, sw = 0.f;
    int j = beg;
    for (; j + 4 <= end; j += 4) {
        int i0 = csr_src[j + 0];
        int i1 = csr_src[j + 1];
        int i2 = csr_src[j + 2];
        int i3 = csr_src[j + 3];
        float4 v0 = *(const float4*)(base + (long)i0 * HID);
        float4 v1 = *(const float4*)(base + (long)i1 * HID);
        float4 v2 = *(const float4*)(base + (long)i2 * HID);
        float4 v3 = *(const float4*)(base + (long)i3 * HID);
        sx += v0.x + v1.x + v2.x + v3.x;
        sy += v0.y + v1.y + v2.y + v3.y;
        sz += v0.z + v1.z + v2.z + v3.z;
        sw += v0.w + v1.w + v2.w + v3.w;
    }
    for (; j < end; ++j) {
        int i0 = csr_src[j];
        float4 v0 = *(const float4*)(base + (long)i0 * HID);
        sx += v0.x; sy += v0.y; sz += v0.z; sw += v0.w;
    }
    float w = invdeg[node];
    float* o = out + (long)node * HID + lane * 4;
    float4 cur = *(float4*)o;
    cur.x += sx * w;
    cur.y += sy * w;
    cur.z += sz * w;
    cur.w += sw * w;
    *(float4*)o = cur;
}

// ---------------------------------------------------------------------------
// BatchNorm: stats -> finalize -> apply(+ReLU)
// apply: if Hhi != null, write bf16 hi/lo split (next GEMM's A operand) ONLY;
//        else write fp32 in place (layer 3, feeds pooling).
// ---------------------------------------------------------------------------
__global__ __launch_bounds__(256) void bn_stats(const float* __restrict__ h,
                                                float* __restrict__ sums) {
    int c    = threadIdx.x & 127;
    int half = threadIdx.x >> 7;
    float s = 0.f, s2 = 0.f;
    for (int r = blockIdx.x * 2 + half; r < N_NODES; r += gridDim.x * 2) {
        float v = h[(long)r * HID + c];
        s  += v;
        s2 += v * v;
    }
    atomicAdd(&sums[c], s);
    atomicAdd(&sums[HID + c], s2);
}

__global__ __launch_bounds__(128) void bn_finalize(const float* __restrict__ sums,
                                                   const float* __restrict__ gamma,
                                                   const float* __restrict__ beta,
                                                   float* __restrict__ ss) {
    int c = threadIdx.x;
    const float invn = 1.0f / (float)N_NODES;
    float mu  = sums[c] * invn;
    float var = sums[HID + c] * invn - mu * mu;
    float sc  = gamma[c] * rsqrtf(var + BN_EPS);
    ss[c]       = sc;
    ss[HID + c] = beta[c] - mu * sc;
}

__global__ __launch_bounds__(256) void bn_apply_relu(float* __restrict__ h,
                                                     const float* __restrict__ ss,
                                                     unsigned short* __restrict__ Hhi,
                                                     unsigned short* __restrict__ Hlo) {
    long i = (long)blockIdx.x * 256 + threadIdx.x;
    if (i >= (long)N_NODES * 32) return;
    int c4 = (int)(i & 31) * 4;
    float4 v  = *(float4*)&h[i * 4];
    float4 sc = *(const float4*)&ss[c4];
    float4 sh = *(const float4*)&ss[HID + c4];
    v.x = fmaxf(v.x * sc.x + sh.x, 0.f);
    v.y = fmaxf(v.y * sc.y + sh.y, 0.f);
    v.z = fmaxf(v.z * sc.z + sh.z, 0.f);
    v.w = fmaxf(v.w * sc.w + sh.w, 0.f);
    if (Hhi) {
        ushort4 hh, ll;
        hh.x = f2bf(v.x); ll.x = f2bf(v.x - bf2f(hh.x));
        hh.y = f2bf(v.y); ll.y = f2bf(v.y - bf2f(hh.y));
        hh.z = f2bf(v.z); ll.z = f2bf(v.z - bf2f(hh.z));
        hh.w = f2bf(v.w); ll.w = f2bf(v.w - bf2f(hh.w));
        *(ushort4*)&Hhi[i * 4] = hh;
        *(ushort4*)&Hlo[i * 4] = ll;
    } else {
        *(float4*)&h[i * 4] = v;
    }
}

// ---------------------------------------------------------------------------
// global mean pool
// ---------------------------------------------------------------------------
#define POOL_ROWS 128
__global__ __launch_bounds__(128) void pool_kernel(const float* __restrict__ h,
                                                   const int* __restrict__ batch,
                                                   float* __restrict__ pooled,
                                                   float* __restrict__ cnt) {
    int c  = threadIdx.x;
    int r0 = blockIdx.x * POOL_ROWS;
    if (r0 >= N_NODES) return;
    int r1 = min(r0 + POOL_ROWS, N_NODES);
    int cur = batch[r0];
    float acc = 0.f, n = 0.f;
    for (int r = r0; r < r1; ++r) {
        int b = batch[r];
        if (b != cur) {
            atomicAdd(&pooled[cur * HID + c], acc);
            if (c == 0) atomicAdd(&cnt[cur], n);
            acc = 0.f;
            n   = 0.f;
            cur = b;
        }
        acc += h[(long)r * HID + c];
        n   += 1.f;
    }
    atomicAdd(&pooled[cur * HID + c], acc);
    if (c == 0) atomicAdd(&cnt[cur], n);
}

// ---------------------------------------------------------------------------
// head
// ---------------------------------------------------------------------------
__global__ __launch_bounds__(128) void head_kernel(const float* __restrict__ pooled,
                                                   const float* __restrict__ cnt,
                                                   const float* __restrict__ Wc,
                                                   const float* __restrict__ bc,
                                                   float* __restrict__ out) {
    int g = threadIdx.x;
    float inv = 1.0f / fmaxf(cnt[g], 1.0f);
    float o0 = bc[0], o1 = bc[1];
    for (int c = 0; c < HID; ++c) {
        float v = pooled[g * HID + c] * inv;
        out[N_GRAPHS * N_CLASSES + g * HID + c] = v;
        o0 += v * Wc[c * 2 + 0];
        o1 += v * Wc[c * 2 + 1];
    }
    out[g * 2 + 0] = o0;
    out[g * 2 + 1] = o1;
}

// ---------------------------------------------------------------------------
// launch
// ---------------------------------------------------------------------------
extern "C" void kernel_launch(void* const* d_in, const int* in_sizes, int n_in,
                              void* d_out, int out_size, void* d_ws, size_t ws_size,
                              hipStream_t stream) {
    const float* x     = (const float*)d_in[0];
    const int*   ei    = (const int*)d_in[1];
    const int*   batch = (const int*)d_in[2];
    const float* W1l = (const float*)d_in[3];
    const float* W1r = (const float*)d_in[4];
    const float* b1  = (const float*)d_in[5];
    const float* g1  = (const float*)d_in[6];
    const float* be1 = (const float*)d_in[7];
    const float* W2l = (const float*)d_in[8];
    const float* W2r = (const float*)d_in[9];
    const float* b2  = (const float*)d_in[10];
    const float* g2  = (const float*)d_in[11];
    const float* be2 = (const float*)d_in[12];
    const float* W3l = (const float*)d_in[13];
    const float* W3r = (const float*)d_in[14];
    const float* b3  = (const float*)d_in[15];
    const float* g3  = (const float*)d_in[16];
    const float* be3 = (const float*)d_in[17];
    const float* Wc  = (const float*)d_in[18];
    const float* bc  = (const float*)d_in[19];

    const int* src = ei;
    const int* dst = ei + N_EDGES;

    float* ws = (float*)d_ws;
    const long FEAT = (long)N_NODES * HID;
    float* buf0 = ws;
    float* buf1 = ws + FEAT;
    float* buf2 = ws + 2 * FEAT;
    int*   ideg      = (int*)(ws + 3 * FEAT);        // 50000
    int*   row_start = ideg + N_NODES;               // 50001 (pad to 50004)
    int*   cursor    = row_start + N_NODES + 4;      // 50000
    int*   csr_src   = cursor + N_NODES;             // 600000
    float* invdeg    = (float*)(csr_src + N_EDGES);  // 50000
    float* sums      = invdeg + N_NODES;             // 256
    float* ss        = sums + 2 * HID;               // 256
    float* pooled    = ss + 2 * HID;                 // 16384
    float* cnt       = pooled + N_GRAPHS * HID;      // 128
    unsigned short* Bhi  = (unsigned short*)(cnt + N_GRAPHS);  // 256*320
    unsigned short* Blo  = Bhi + 256 * KP1;                    // 256*320
    unsigned short* Axhi = Blo + 256 * KP1;                    // 50000*320
    unsigned short* Axlo = Axhi + (long)N_NODES * KP1;         // 50000*320
    unsigned short* Hhi  = Axlo + (long)N_NODES * KP1;         // 50000*128
    unsigned short* Hlo  = Hhi + FEAT;                         // 50000*128

    float* outp = (float*)d_out;

    const int gemm_grid   = (N_NODES + 63) / 64;     // 782
    const int gather_grid = (N_NODES + 7) / 8;
    const int apply_grid  = (int)(((long)N_NODES * 32 + 255) / 256);
    const int pool_grid   = (N_NODES + POOL_ROWS - 1) / POOL_ROWS;
    const int prepx_grid  = (N_NODES * (KP1 / 4) + 255) / 256;

    // --- CSR build (once per call) ---
    hipMemsetAsync(ideg, 0, N_NODES * sizeof(int), stream);
    hipMemsetAsync(cursor, 0, N_NODES * sizeof(int), stream);
    deg_kernel<<<(N_EDGES + 255) / 256, 256, 0, stream>>>(dst, ideg);
    invdeg_kernel<<<(N_NODES + 255) / 256, 256, 0, stream>>>(ideg, invdeg);
    scan_kernel<<<1, SCAN_T, 0, stream>>>(ideg, row_start);
    fill_kernel<<<(N_EDGES + 255) / 256, 256, 0, stream>>>(src, dst, row_start, cursor, csr_src);

    // --- split x (A operand for layer 1) ---
    prep_x<<<prepx_grid, 256, 0, stream>>>(x, Axhi, Axlo);

    // ---------------- layer 1 (A=x split, Kp=320) ----------------
    prep_w<<<(256 * KP1 + 255) / 256, 256, 0, stream>>>(W1l, W1r, IN_CH, KP1, Bhi, Blo);
    gemm_mfma<<<gemm_grid, 256, 0, stream>>>(Axhi, Axlo, N_NODES, KP1, Bhi, Blo, b1, buf0, buf1);
    gather_agg<<<gather_grid, 256, 0, stream>>>(buf0, row_start, csr_src, invdeg, buf1);
    hipMemsetAsync(sums, 0, 2 * HID * sizeof(float), stream);
    bn_stats<<<256, 256, 0, stream>>>(buf1, sums);
    bn_finalize<<<1, 128, 0, stream>>>(sums, g1, be1, ss);
    bn_apply_relu<<<apply_grid, 256, 0, stream>>>(buf1, ss, Hhi, Hlo);

    // ---------------- layer 2 (A=h1 split, Kp=128) ----------------
    prep_w<<<(256 * HID + 255) / 256, 256, 0, stream>>>(W2l, W2r, HID, HID, Bhi, Blo);
    gemm_mfma<<<gemm_grid, 256, 0, stream>>>(Hhi, Hlo, N_NODES, HID, Bhi, Blo, b2, buf0, buf2);
    gather_agg<<<gather_grid, 256, 0, stream>>>(buf0, row_start, csr_src, invdeg, buf2);
    hipMemsetAsync(sums, 0, 2 * HID * sizeof(float), stream);
    bn_stats<<<256, 256, 0, stream>>>(buf2, sums);
    bn_finalize<<<1, 128, 0, stream>>>(sums, g2, be2, ss);
    bn_apply_relu<<<apply_grid, 256, 0, stream>>>(buf2, ss, Hhi, Hlo);

    // ---------------- layer 3 (A=h2 split, Kp=128) ----------------
    prep_w<<<(256 * HID + 255) / 256, 256, 0, stream>>>(W3l, W3r, HID, HID, Bhi, Blo);
    gemm_mfma<<<gemm_grid, 256, 0, stream>>>(Hhi, Hlo, N_NODES, HID, Bhi, Blo, b3, buf0, buf1);
    gather_agg<<<gather_grid, 256, 0, stream>>>(buf0, row_start, csr_src, invdeg, buf1);
    hipMemsetAsync(sums, 0, 2 * HID * sizeof(float), stream);
    bn_stats<<<256, 256, 0, stream>>>(buf1, sums);
    bn_finalize<<<1, 128, 0, stream>>>(sums, g3, be3, ss);
    bn_apply_relu<<<apply_grid, 256, 0, stream>>>(buf1, ss, nullptr, nullptr);  // fp32 in place

    // ---------------- pool + head ----------------
    hipMemsetAsync(pooled, 0, (N_GRAPHS * HID + N_GRAPHS) * sizeof(float), stream);
    pool_kernel<<<pool_grid, 128, 0, stream>>>(buf1, batch, pooled, cnt);
    head_kernel<<<1, 128, 0, stream>>>(pooled, cnt, Wc, bc, outp);
}

// Round 5
// 737.832 us; speedup vs baseline: 1.0668x; 1.0668x over previous
//
#include <hip/hip_runtime.h>

#define N_NODES   50000
#define N_EDGES   600000
#define IN_CH     300
#define HID       128
#define N_CLASSES 2
#define N_GRAPHS  128
#define BN_EPS    1e-5f

typedef __attribute__((ext_vector_type(8))) short bf8_t;   // 8 bf16 (4 VGPRs)
typedef __attribute__((ext_vector_type(4))) float f4_t;    // MFMA acc
typedef unsigned short ushort_t;

// bf16 round-to-nearest-even helpers
__device__ __forceinline__ unsigned short f2bf(float x) {
    union { float f; unsigned u; } q; q.f = x;
    unsigned r = q.u + 0x7fffu + ((q.u >> 16) & 1u);
    return (unsigned short)(r >> 16);
}
__device__ __forceinline__ float bf2f(unsigned short h) {
    union { float f; unsigned u; } q; q.u = ((unsigned)h) << 16; return q.f;
}

// async global->LDS 16B copy: LDS dest = wave-uniform base + lane*16
__device__ __forceinline__ void async_cp16(const void* g, void* l) {
    __builtin_amdgcn_global_load_lds(
        (const __attribute__((address_space(1))) unsigned int*)g,
        (__attribute__((address_space(3))) unsigned int*)l, 16, 0, 0);
}

// ---------------------------------------------------------------------------
// CSR construction: degree count -> scan -> bucket fill
// ---------------------------------------------------------------------------
__global__ __launch_bounds__(256) void deg_kernel(const int* __restrict__ dst,
                                                  int* __restrict__ ideg) {
    int e = blockIdx.x * 256 + threadIdx.x;
    if (e < N_EDGES) atomicAdd(&ideg[dst[e]], 1);
}

__global__ __launch_bounds__(256) void invdeg_kernel(const int* __restrict__ ideg,
                                                     float* __restrict__ invdeg) {
    int i = blockIdx.x * 256 + threadIdx.x;
    if (i < N_NODES) invdeg[i] = 1.0f / fmaxf((float)ideg[i], 1.0f);
}

#define SCAN_T 1024
__global__ __launch_bounds__(SCAN_T) void scan_kernel(const int* __restrict__ ideg,
                                                      int* __restrict__ row_start) {
    __shared__ int part[SCAN_T];
    int t = threadIdx.x;
    const int chunk = (N_NODES + SCAN_T - 1) / SCAN_T;
    int b = t * chunk;
    int e = min(b + chunk, N_NODES);
    int s = 0;
    for (int i = b; i < e; ++i) s += ideg[i];
    part[t] = s;
    __syncthreads();
    for (int off = 1; off < SCAN_T; off <<= 1) {
        int v = (t >= off) ? part[t - off] : 0;
        __syncthreads();
        part[t] += v;
        __syncthreads();
    }
    int run = (t == 0) ? 0 : part[t - 1];
    for (int i = b; i < e; ++i) {
        row_start[i] = run;
        run += ideg[i];
    }
    if (t == SCAN_T - 1) row_start[N_NODES] = run;
}

__global__ __launch_bounds__(256) void fill_kernel(const int* __restrict__ src,
                                                   const int* __restrict__ dst,
                                                   const int* __restrict__ row_start,
                                                   int* __restrict__ cursor,
                                                   int* __restrict__ csr_src) {
    int e = blockIdx.x * 256 + threadIdx.x;
    if (e >= N_EDGES) return;
    int d = dst[e];
    int pos = row_start[d] + atomicAdd(&cursor[d], 1);
    csr_src[pos] = src[e];
}

// ---------------------------------------------------------------------------
// x -> split bf16 hi/lo planes (M x 320, zero-padded cols 300..319)
// ---------------------------------------------------------------------------
#define KP1 320
__global__ __launch_bounds__(256) void prep_x(const float* __restrict__ x,
                                              unsigned short* __restrict__ Ahi,
                                              unsigned short* __restrict__ Alo) {
    int idx = blockIdx.x * 256 + threadIdx.x;  // over N_NODES * 80
    if (idx >= N_NODES * (KP1 / 4)) return;
    int row = idx / (KP1 / 4);
    int c4  = (idx - row * (KP1 / 4)) * 4;
    float4 v = make_float4(0.f, 0.f, 0.f, 0.f);
    if (c4 < IN_CH) v = *(const float4*)&x[(long)row * IN_CH + c4];
    ushort4 h, l;
    h.x = f2bf(v.x); l.x = f2bf(v.x - bf2f(h.x));
    h.y = f2bf(v.y); l.y = f2bf(v.y - bf2f(h.y));
    h.z = f2bf(v.z); l.z = f2bf(v.z - bf2f(h.z));
    h.w = f2bf(v.w); l.w = f2bf(v.w - bf2f(h.w));
    *(ushort4*)&Ahi[(long)row * KP1 + c4] = h;
    *(ushort4*)&Alo[(long)row * KP1 + c4] = l;
}

// ---------------------------------------------------------------------------
// weight prep: BT[n][k] (256 x Kp, bf16 hi/lo, zero-padded k>=K)
// ---------------------------------------------------------------------------
__global__ __launch_bounds__(256) void prep_w(const float* __restrict__ Wl,
                                              const float* __restrict__ Wr,
                                              int K, int Kp,
                                              unsigned short* __restrict__ Bhi,
                                              unsigned short* __restrict__ Blo) {
    int idx = blockIdx.x * 256 + threadIdx.x;
    if (idx >= 256 * Kp) return;
    int n = idx / Kp;
    int k = idx - n * Kp;
    float v = 0.f;
    if (k < K) v = (n < 128) ? Wl[k * 128 + n] : Wr[k * 128 + (n - 128)];
    unsigned short h = f2bf(v);
    unsigned short l = f2bf(v - bf2f(h));
    Bhi[idx] = h;
    Blo[idx] = l;
}

// ---------------------------------------------------------------------------
// split-bf16 MFMA GEMM (m97-style LDS staging):
//   C0 = A@Wl , C1 = A@Wr + bias   (N = 128+128)
// block tile 64(M) x 256(N), 4 waves, wave tile 64x64 = 4x4 MFMA 16x16x32.
// K-loop BK=32: async global_load_lds staging of A(64x32) + B(256x32) hi/lo
// (40 KB LDS), 2-barrier single-buffer. Dekker 3-product fp32 emulation.
// ---------------------------------------------------------------------------
__global__ __launch_bounds__(256) void gemm_mfma(const unsigned short* __restrict__ Ahi,
                                                 const unsigned short* __restrict__ Alo,
                                                 int M, int Kp,
                                                 const unsigned short* __restrict__ Bhi,
                                                 const unsigned short* __restrict__ Blo,
                                                 const float* __restrict__ bias,
                                                 float* __restrict__ C0,
                                                 float* __restrict__ C1) {
    __shared__ __align__(16) unsigned short sAh[64 * 32];
    __shared__ __align__(16) unsigned short sAl[64 * 32];
    __shared__ __align__(16) unsigned short sBh[256 * 32];
    __shared__ __align__(16) unsigned short sBl[256 * 32];

    const int tid  = threadIdx.x;
    const int lane = tid & 63;
    const int wave = tid >> 6;
    const int l16  = lane & 15;
    const int quad = lane >> 4;
    const long m0  = (long)blockIdx.x * 64;
    const int  n0  = wave * 64;

    f4_t acc[4][4];
#pragma unroll
    for (int mt = 0; mt < 4; ++mt)
#pragma unroll
        for (int nt = 0; nt < 4; ++nt) acc[mt][nt] = (f4_t){0.f, 0.f, 0.f, 0.f};

    // --- staging addresses ---
    // A: wave w stages rows m0 + w*16 + lane/4, ushort col (lane&3)*8
    long asr = m0 + wave * 16 + (lane >> 2);
    if (asr >= M) asr = M - 1;  // clamp: garbage rows never stored
    const unsigned short* gAh = Ahi + asr * Kp + (lane & 3) * 8;
    const unsigned short* gAl = Alo + asr * Kp + (lane & 3) * 8;
    unsigned short* lAh = &sAh[wave * 512];   // byte off wave*1024, +lane*16 by HW
    unsigned short* lAl = &sAl[wave * 512];
    // B: wave w iter j stages rows w*64 + j*16 + lane/4
    const unsigned short* gBh[4];
    const unsigned short* gBl[4];
    unsigned short* lBh[4];
    unsigned short* lBl[4];
#pragma unroll
    for (int j = 0; j < 4; ++j) {
        long br = wave * 64 + j * 16 + (lane >> 2);
        gBh[j] = Bhi + br * Kp + (lane & 3) * 8;
        gBl[j] = Blo + br * Kp + (lane & 3) * 8;
        lBh[j] = &sBh[wave * 2048 + j * 512];
        lBl[j] = &sBl[wave * 2048 + j * 512];
    }

    for (int k0 = 0; k0 < Kp; k0 += 32) {
        // ---- stage (async, 10 x 16B per lane-group) ----
        async_cp16(gAh + k0, lAh);
        async_cp16(gAl + k0, lAl);
#pragma unroll
        for (int j = 0; j < 4; ++j) {
            async_cp16(gBh[j] + k0, lBh[j]);
            async_cp16(gBl[j] + k0, lBl[j]);
        }
        __syncthreads();   // drains vmcnt (global_load_lds) for all waves

        // ---- fragments from LDS + MFMA ----
        bf8_t ah[4], al[4];
#pragma unroll
        for (int mt = 0; mt < 4; ++mt) {
            ah[mt] = *(const bf8_t*)&sAh[(mt * 16 + l16) * 32 + quad * 8];
            al[mt] = *(const bf8_t*)&sAl[(mt * 16 + l16) * 32 + quad * 8];
        }
#pragma unroll
        for (int nt = 0; nt < 4; ++nt) {
            bf8_t bh = *(const bf8_t*)&sBh[(n0 + nt * 16 + l16) * 32 + quad * 8];
            bf8_t bl = *(const bf8_t*)&sBl[(n0 + nt * 16 + l16) * 32 + quad * 8];
#pragma unroll
            for (int mt = 0; mt < 4; ++mt) {
                acc[mt][nt] = __builtin_amdgcn_mfma_f32_16x16x32_bf16(ah[mt], bh, acc[mt][nt], 0, 0, 0);
                acc[mt][nt] = __builtin_amdgcn_mfma_f32_16x16x32_bf16(al[mt], bh, acc[mt][nt], 0, 0, 0);
                acc[mt][nt] = __builtin_amdgcn_mfma_f32_16x16x32_bf16(ah[mt], bl, acc[mt][nt], 0, 0, 0);
            }
        }
        __syncthreads();   // protect LDS before next stage overwrites
    }

    // epilogue: wave-uniform half selection (n0<128 -> C0, else C1 + bias)
    const bool left = (n0 < 128);
    float* __restrict__ Cb = left ? C0 : C1;
    float badd[4];
    int   ncol[4];
#pragma unroll
    for (int nt = 0; nt < 4; ++nt) {
        int ng = n0 + nt * 16 + l16;
        ncol[nt] = left ? ng : (ng - 128);
        badd[nt] = left ? 0.f : bias[ng - 128];
    }
#pragma unroll
    for (int mt = 0; mt < 4; ++mt) {
#pragma unroll
        for (int r = 0; r < 4; ++r) {
            long row = m0 + mt * 16 + quad * 4 + r;
            if (row < M) {
#pragma unroll
                for (int nt = 0; nt < 4; ++nt)
                    Cb[row * 128 + ncol[nt]] = acc[mt][nt][r] + badd[nt];
            }
        }
    }
}

// ---------------------------------------------------------------------------
// CSR gather: out[n] += invdeg[n] * sum_{j in adj(n)} Pl[csr_src[j]]
// 32 lanes/node (float4/lane), 8 nodes/block, 4-edge unroll for MLP.
// ---------------------------------------------------------------------------
__global__ __launch_bounds__(256) void gather_agg(const float* __restrict__ Pl,
                                                  const int* __restrict__ row_start,
                                                  const int* __restrict__ csr_src,
                                                  const float* __restrict__ invdeg,
                                                  float* __restrict__ out) {
    int slot = threadIdx.x >> 5;
    int lane = threadIdx.x & 31;
    int node = blockIdx.x * 8 + slot;
    if (node >= N_NODES) return;
    int beg = row_start[node];
    int end = row_start[node + 1];
    const float* base = Pl + lane * 4;
    float sx = 0.f, sy = 0.f, sz = 0.f, sw = 0.f;
    int j = beg;
    for (; j + 4 <= end; j += 4) {
        int i0 = csr_src[j + 0];
        int i1 = csr_src[j + 1];
        int i2 = csr_src[j + 2];
        int i3 = csr_src[j + 3];
        float4 v0 = *(const float4*)(base + (long)i0 * HID);
        float4 v1 = *(const float4*)(base + (long)i1 * HID);
        float4 v2 = *(const float4*)(base + (long)i2 * HID);
        float4 v3 = *(const float4*)(base + (long)i3 * HID);
        sx += v0.x + v1.x + v2.x + v3.x;
        sy += v0.y + v1.y + v2.y + v3.y;
        sz += v0.z + v1.z + v2.z + v3.z;
        sw += v0.w + v1.w + v2.w + v3.w;
    }
    for (; j < end; ++j) {
        int i0 = csr_src[j];
        float4 v0 = *(const float4*)(base + (long)i0 * HID);
        sx += v0.x; sy += v0.y; sz += v0.z; sw += v0.w;
    }
    float w = invdeg[node];
    float* o = out + (long)node * HID + lane * 4;
    float4 cur = *(float4*)o;
    cur.x += sx * w;
    cur.y += sy * w;
    cur.z += sz * w;
    cur.w += sw * w;
    *(float4*)o = cur;
}

// ---------------------------------------------------------------------------
// BatchNorm: stats -> finalize -> apply(+ReLU)
// ---------------------------------------------------------------------------
__global__ __launch_bounds__(256) void bn_stats(const float* __restrict__ h,
                                                float* __restrict__ sums) {
    int c    = threadIdx.x & 127;
    int half = threadIdx.x >> 7;
    float s = 0.f, s2 = 0.f;
    for (int r = blockIdx.x * 2 + half; r < N_NODES; r += gridDim.x * 2) {
        float v = h[(long)r * HID + c];
        s  += v;
        s2 += v * v;
    }
    atomicAdd(&sums[c], s);
    atomicAdd(&sums[HID + c], s2);
}

__global__ __launch_bounds__(128) void bn_finalize(const float* __restrict__ sums,
                                                   const float* __restrict__ gamma,
                                                   const float* __restrict__ beta,
                                                   float* __restrict__ ss) {
    int c = threadIdx.x;
    const float invn = 1.0f / (float)N_NODES;
    float mu  = sums[c] * invn;
    float var = sums[HID + c] * invn - mu * mu;
    float sc  = gamma[c] * rsqrtf(var + BN_EPS);
    ss[c]       = sc;
    ss[HID + c] = beta[c] - mu * sc;
}

__global__ __launch_bounds__(256) void bn_apply_relu(float* __restrict__ h,
                                                     const float* __restrict__ ss,
                                                     unsigned short* __restrict__ Hhi,
                                                     unsigned short* __restrict__ Hlo) {
    long i = (long)blockIdx.x * 256 + threadIdx.x;
    if (i >= (long)N_NODES * 32) return;
    int c4 = (int)(i & 31) * 4;
    float4 v  = *(float4*)&h[i * 4];
    float4 sc = *(const float4*)&ss[c4];
    float4 sh = *(const float4*)&ss[HID + c4];
    v.x = fmaxf(v.x * sc.x + sh.x, 0.f);
    v.y = fmaxf(v.y * sc.y + sh.y, 0.f);
    v.z = fmaxf(v.z * sc.z + sh.z, 0.f);
    v.w = fmaxf(v.w * sc.w + sh.w, 0.f);
    if (Hhi) {
        ushort4 hh, ll;
        hh.x = f2bf(v.x); ll.x = f2bf(v.x - bf2f(hh.x));
        hh.y = f2bf(v.y); ll.y = f2bf(v.y - bf2f(hh.y));
        hh.z = f2bf(v.z); ll.z = f2bf(v.z - bf2f(hh.z));
        hh.w = f2bf(v.w); ll.w = f2bf(v.w - bf2f(hh.w));
        *(ushort4*)&Hhi[i * 4] = hh;
        *(ushort4*)&Hlo[i * 4] = ll;
    } else {
        *(float4*)&h[i * 4] = v;
    }
}

// ---------------------------------------------------------------------------
// global mean pool
// ---------------------------------------------------------------------------
#define POOL_ROWS 128
__global__ __launch_bounds__(128) void pool_kernel(const float* __restrict__ h,
                                                   const int* __restrict__ batch,
                                                   float* __restrict__ pooled,
                                                   float* __restrict__ cnt) {
    int c  = threadIdx.x;
    int r0 = blockIdx.x * POOL_ROWS;
    if (r0 >= N_NODES) return;
    int r1 = min(r0 + POOL_ROWS, N_NODES);
    int cur = batch[r0];
    float acc = 0.f, n = 0.f;
    for (int r = r0; r < r1; ++r) {
        int b = batch[r];
        if (b != cur) {
            atomicAdd(&pooled[cur * HID + c], acc);
            if (c == 0) atomicAdd(&cnt[cur], n);
            acc = 0.f;
            n   = 0.f;
            cur = b;
        }
        acc += h[(long)r * HID + c];
        n   += 1.f;
    }
    atomicAdd(&pooled[cur * HID + c], acc);
    if (c == 0) atomicAdd(&cnt[cur], n);
}

// ---------------------------------------------------------------------------
// head
// ---------------------------------------------------------------------------
__global__ __launch_bounds__(128) void head_kernel(const float* __restrict__ pooled,
                                                   const float* __restrict__ cnt,
                                                   const float* __restrict__ Wc,
                                                   const float* __restrict__ bc,
                                                   float* __restrict__ out) {
    int g = threadIdx.x;
    float inv = 1.0f / fmaxf(cnt[g], 1.0f);
    float o0 = bc[0], o1 = bc[1];
    for (int c = 0; c < HID; ++c) {
        float v = pooled[g * HID + c] * inv;
        out[N_GRAPHS * N_CLASSES + g * HID + c] = v;
        o0 += v * Wc[c * 2 + 0];
        o1 += v * Wc[c * 2 + 1];
    }
    out[g * 2 + 0] = o0;
    out[g * 2 + 1] = o1;
}

// ---------------------------------------------------------------------------
// launch
// ---------------------------------------------------------------------------
extern "C" void kernel_launch(void* const* d_in, const int* in_sizes, int n_in,
                              void* d_out, int out_size, void* d_ws, size_t ws_size,
                              hipStream_t stream) {
    const float* x     = (const float*)d_in[0];
    const int*   ei    = (const int*)d_in[1];
    const int*   batch = (const int*)d_in[2];
    const float* W1l = (const float*)d_in[3];
    const float* W1r = (const float*)d_in[4];
    const float* b1  = (const float*)d_in[5];
    const float* g1  = (const float*)d_in[6];
    const float* be1 = (const float*)d_in[7];
    const float* W2l = (const float*)d_in[8];
    const float* W2r = (const float*)d_in[9];
    const float* b2  = (const float*)d_in[10];
    const float* g2  = (const float*)d_in[11];
    const float* be2 = (const float*)d_in[12];
    const float* W3l = (const float*)d_in[13];
    const float* W3r = (const float*)d_in[14];
    const float* b3  = (const float*)d_in[15];
    const float* g3  = (const float*)d_in[16];
    const float* be3 = (const float*)d_in[17];
    const float* Wc  = (const float*)d_in[18];
    const float* bc  = (const float*)d_in[19];

    const int* src = ei;
    const int* dst = ei + N_EDGES;

    float* ws = (float*)d_ws;
    const long FEAT = (long)N_NODES * HID;
    float* buf0 = ws;
    float* buf1 = ws + FEAT;
    float* buf2 = ws + 2 * FEAT;
    int*   ideg      = (int*)(ws + 3 * FEAT);        // 50000
    int*   row_start = ideg + N_NODES;               // 50001 (pad to 50004)
    int*   cursor    = row_start + N_NODES + 4;      // 50000
    int*   csr_src   = cursor + N_NODES;             // 600000
    float* invdeg    = (float*)(csr_src + N_EDGES);  // 50000
    float* sums      = invdeg + N_NODES;             // 256
    float* ss        = sums + 2 * HID;               // 256
    float* pooled    = ss + 2 * HID;                 // 16384
    float* cnt       = pooled + N_GRAPHS * HID;      // 128
    unsigned short* Bhi  = (unsigned short*)(cnt + N_GRAPHS);  // 256*320
    unsigned short* Blo  = Bhi + 256 * KP1;                    // 256*320
    unsigned short* Axhi = Blo + 256 * KP1;                    // 50000*320
    unsigned short* Axlo = Axhi + (long)N_NODES * KP1;         // 50000*320
    unsigned short* Hhi  = Axlo + (long)N_NODES * KP1;         // 50000*128
    unsigned short* Hlo  = Hhi + FEAT;                         // 50000*128

    float* outp = (float*)d_out;

    const int gemm_grid   = (N_NODES + 63) / 64;     // 782
    const int gather_grid = (N_NODES + 7) / 8;
    const int apply_grid  = (int)(((long)N_NODES * 32 + 255) / 256);
    const int pool_grid   = (N_NODES + POOL_ROWS - 1) / POOL_ROWS;
    const int prepx_grid  = (N_NODES * (KP1 / 4) + 255) / 256;

    // --- CSR build (once per call) ---
    hipMemsetAsync(ideg, 0, N_NODES * sizeof(int), stream);
    hipMemsetAsync(cursor, 0, N_NODES * sizeof(int), stream);
    deg_kernel<<<(N_EDGES + 255) / 256, 256, 0, stream>>>(dst, ideg);
    invdeg_kernel<<<(N_NODES + 255) / 256, 256, 0, stream>>>(ideg, invdeg);
    scan_kernel<<<1, SCAN_T, 0, stream>>>(ideg, row_start);
    fill_kernel<<<(N_EDGES + 255) / 256, 256, 0, stream>>>(src, dst, row_start, cursor, csr_src);

    // --- split x (A operand for layer 1) ---
    prep_x<<<prepx_grid, 256, 0, stream>>>(x, Axhi, Axlo);

    // ---------------- layer 1 (A=x split, Kp=320) ----------------
    prep_w<<<(256 * KP1 + 255) / 256, 256, 0, stream>>>(W1l, W1r, IN_CH, KP1, Bhi, Blo);
    gemm_mfma<<<gemm_grid, 256, 0, stream>>>(Axhi, Axlo, N_NODES, KP1, Bhi, Blo, b1, buf0, buf1);
    gather_agg<<<gather_grid, 256, 0, stream>>>(buf0, row_start, csr_src, invdeg, buf1);
    hipMemsetAsync(sums, 0, 2 * HID * sizeof(float), stream);
    bn_stats<<<256, 256, 0, stream>>>(buf1, sums);
    bn_finalize<<<1, 128, 0, stream>>>(sums, g1, be1, ss);
    bn_apply_relu<<<apply_grid, 256, 0, stream>>>(buf1, ss, Hhi, Hlo);

    // ---------------- layer 2 (A=h1 split, Kp=128) ----------------
    prep_w<<<(256 * HID + 255) / 256, 256, 0, stream>>>(W2l, W2r, HID, HID, Bhi, Blo);
    gemm_mfma<<<gemm_grid, 256, 0, stream>>>(Hhi, Hlo, N_NODES, HID, Bhi, Blo, b2, buf0, buf2);
    gather_agg<<<gather_grid, 256, 0, stream>>>(buf0, row_start, csr_src, invdeg, buf2);
    hipMemsetAsync(sums, 0, 2 * HID * sizeof(float), stream);
    bn_stats<<<256, 256, 0, stream>>>(buf2, sums);
    bn_finalize<<<1, 128, 0, stream>>>(sums, g2, be2, ss);
    bn_apply_relu<<<apply_grid, 256, 0, stream>>>(buf2, ss, Hhi, Hlo);

    // ---------------- layer 3 (A=h2 split, Kp=128) ----------------
    prep_w<<<(256 * HID + 255) / 256, 256, 0, stream>>>(W3l, W3r, HID, HID, Bhi, Blo);
    gemm_mfma<<<gemm_grid, 256, 0, stream>>>(Hhi, Hlo, N_NODES, HID, Bhi, Blo, b3, buf0, buf1);
    gather_agg<<<gather_grid, 256, 0, stream>>>(buf0, row_start, csr_src, invdeg, buf1);
    hipMemsetAsync(sums, 0, 2 * HID * sizeof(float), stream);
    bn_stats<<<256, 256, 0, stream>>>(buf1, sums);
    bn_finalize<<<1, 128, 0, stream>>>(sums, g3, be3, ss);
    bn_apply_relu<<<apply_grid, 256, 0, stream>>>(buf1, ss, nullptr, nullptr);  // fp32 in place

    // ---------------- pool + head ----------------
    hipMemsetAsync(pooled, 0, (N_GRAPHS * HID + N_GRAPHS) * sizeof(float), stream);
    pool_kernel<<<pool_grid, 128, 0, stream>>>(buf1, batch, pooled, cnt);
    head_kernel<<<1, 128, 0, stream>>>(pooled, cnt, Wc, bc, outp);
}

// Round 6
// 667.094 us; speedup vs baseline: 1.1800x; 1.1060x over previous
//
#include <hip/hip_runtime.h>

#define N_NODES   50000
#define N_EDGES   600000
#define IN_CH     300
#define HID       128
#define N_CLASSES 2
#define N_GRAPHS  128
#define BN_EPS    1e-5f

#define NB ((N_NODES + 511) / 512)   // scan blocks = 98

typedef __attribute__((ext_vector_type(8))) short bf8_t;   // 8 bf16 (4 VGPRs)
typedef __attribute__((ext_vector_type(4))) float f4_t;    // MFMA acc

// bf16 round-to-nearest-even helpers
__device__ __forceinline__ unsigned short f2bf(float x) {
    union { float f; unsigned u; } q; q.f = x;
    unsigned r = q.u + 0x7fffu + ((q.u >> 16) & 1u);
    return (unsigned short)(r >> 16);
}
__device__ __forceinline__ float bf2f(unsigned short h) {
    union { float f; unsigned u; } q; q.u = ((unsigned)h) << 16; return q.f;
}

// async global->LDS 16B copy: LDS dest = wave-uniform base + lane*16
__device__ __forceinline__ void async_cp16(const void* g, void* l) {
    __builtin_amdgcn_global_load_lds(
        (const __attribute__((address_space(1))) unsigned int*)g,
        (__attribute__((address_space(3))) unsigned int*)l, 16, 0, 0);
}

// ---------------------------------------------------------------------------
// degree count
// ---------------------------------------------------------------------------
__global__ __launch_bounds__(256) void deg_kernel(const int* __restrict__ dst,
                                                  int* __restrict__ ideg) {
    int e = blockIdx.x * 256 + threadIdx.x;
    if (e < N_EDGES) atomicAdd(&ideg[dst[e]], 1);
}

// ---------------------------------------------------------------------------
// 3-phase exclusive scan of ideg -> row_start (+ invdeg fused in phase 3)
// ---------------------------------------------------------------------------
__global__ __launch_bounds__(256) void scan_p1(const int* __restrict__ ideg,
                                               int* __restrict__ bsum) {
    int b = blockIdx.x, t = threadIdx.x;
    int i0 = b * 512 + t * 2;
    int s = 0;
    if (i0 < N_NODES) {                       // N_NODES even -> i0+1 valid too
        int2 v = *(const int2*)&ideg[i0];
        s = v.x + v.y;
    }
#pragma unroll
    for (int d = 1; d < 64; d <<= 1) s += __shfl_down(s, d);
    __shared__ int ws[4];
    int lane = t & 63, wv = t >> 6;
    if (lane == 0) ws[wv] = s;
    __syncthreads();
    if (t == 0) bsum[b] = ws[0] + ws[1] + ws[2] + ws[3];
}

__global__ __launch_bounds__(128) void scan_p2(int* __restrict__ bsum,
                                               int* __restrict__ row_start) {
    __shared__ int sh[128];
    int t = threadIdx.x;
    int v = (t < NB) ? bsum[t] : 0;
    sh[t] = v;
    __syncthreads();
#pragma unroll
    for (int off = 1; off < 128; off <<= 1) {
        int u = (t >= off) ? sh[t - off] : 0;
        __syncthreads();
        sh[t] += u;
        __syncthreads();
    }
    if (t < NB) bsum[t] = sh[t] - v;          // exclusive
    if (t == NB - 1) row_start[N_NODES] = sh[t];
}

__global__ __launch_bounds__(256) void scan_p3(const int* __restrict__ ideg,
                                               const int* __restrict__ bsum,
                                               int* __restrict__ row_start,
                                               float* __restrict__ invdeg) {
    int b = blockIdx.x, t = threadIdx.x;
    int lane = t & 63, wv = t >> 6;
    int i0 = b * 512 + t * 2;
    int v0 = 0, v1 = 0;
    if (i0 < N_NODES) {
        int2 v = *(const int2*)&ideg[i0];
        v0 = v.x; v1 = v.y;
    }
    int tot = v0 + v1;
    int s = tot;
#pragma unroll
    for (int d = 1; d < 64; d <<= 1) {
        int u = __shfl_up(s, d);
        if (lane >= d) s += u;
    }
    __shared__ int ws[4];
    if (lane == 63) ws[wv] = s;
    __syncthreads();
    int woff = 0;
    for (int w = 0; w < wv; ++w) woff += ws[w];
    int base = bsum[b] + woff + (s - tot);    // exclusive prefix for i0
    if (i0 < N_NODES) {
        row_start[i0]     = base;
        row_start[i0 + 1] = base + v0;
        invdeg[i0]     = 1.0f / fmaxf((float)v0, 1.0f);
        invdeg[i0 + 1] = 1.0f / fmaxf((float)v1, 1.0f);
    }
}

__global__ __launch_bounds__(256) void fill_kernel(const int* __restrict__ src,
                                                   const int* __restrict__ dst,
                                                   const int* __restrict__ row_start,
                                                   int* __restrict__ cursor,
                                                   int* __restrict__ csr_src) {
    int e = blockIdx.x * 256 + threadIdx.x;
    if (e >= N_EDGES) return;
    int d = dst[e];
    int pos = row_start[d] + atomicAdd(&cursor[d], 1);
    csr_src[pos] = src[e];
}

// ---------------------------------------------------------------------------
// x -> split bf16 hi/lo planes (M x 320, zero-padded cols 300..319)
// ---------------------------------------------------------------------------
#define KP1 320
__global__ __launch_bounds__(256) void prep_x(const float* __restrict__ x,
                                              unsigned short* __restrict__ Ahi,
                                              unsigned short* __restrict__ Alo) {
    int idx = blockIdx.x * 256 + threadIdx.x;  // over N_NODES * 80
    if (idx >= N_NODES * (KP1 / 4)) return;
    int row = idx / (KP1 / 4);
    int c4  = (idx - row * (KP1 / 4)) * 4;
    float4 v = make_float4(0.f, 0.f, 0.f, 0.f);
    if (c4 < IN_CH) v = *(const float4*)&x[(long)row * IN_CH + c4];
    ushort4 h, l;
    h.x = f2bf(v.x); l.x = f2bf(v.x - bf2f(h.x));
    h.y = f2bf(v.y); l.y = f2bf(v.y - bf2f(h.y));
    h.z = f2bf(v.z); l.z = f2bf(v.z - bf2f(h.z));
    h.w = f2bf(v.w); l.w = f2bf(v.w - bf2f(h.w));
    *(ushort4*)&Ahi[(long)row * KP1 + c4] = h;
    *(ushort4*)&Alo[(long)row * KP1 + c4] = l;
}

// ---------------------------------------------------------------------------
// weight prep: BT[n][k] (256 x Kp, bf16 hi/lo, zero-padded k>=K)
// ---------------------------------------------------------------------------
__global__ __launch_bounds__(256) void prep_w(const float* __restrict__ Wl,
                                              const float* __restrict__ Wr,
                                              int K, int Kp,
                                              unsigned short* __restrict__ Bhi,
                                              unsigned short* __restrict__ Blo) {
    int idx = blockIdx.x * 256 + threadIdx.x;
    if (idx >= 256 * Kp) return;
    int n = idx / Kp;
    int k = idx - n * Kp;
    float v = 0.f;
    if (k < K) v = (n < 128) ? Wl[k * 128 + n] : Wr[k * 128 + (n - 128)];
    unsigned short h = f2bf(v);
    unsigned short l = f2bf(v - bf2f(h));
    Bhi[idx] = h;
    Blo[idx] = l;
}

// ---------------------------------------------------------------------------
// split-bf16 MFMA GEMM (LDS staging):  C0 = A@Wl , C1 = A@Wr + bias
// block tile 64(M) x 256(N), 4 waves, wave tile 64x64 = 4x4 MFMA 16x16x32.
// ---------------------------------------------------------------------------
__global__ __launch_bounds__(256) void gemm_mfma(const unsigned short* __restrict__ Ahi,
                                                 const unsigned short* __restrict__ Alo,
                                                 int M, int Kp,
                                                 const unsigned short* __restrict__ Bhi,
                                                 const unsigned short* __restrict__ Blo,
                                                 const float* __restrict__ bias,
                                                 float* __restrict__ C0,
                                                 float* __restrict__ C1) {
    __shared__ __align__(16) unsigned short sAh[64 * 32];
    __shared__ __align__(16) unsigned short sAl[64 * 32];
    __shared__ __align__(16) unsigned short sBh[256 * 32];
    __shared__ __align__(16) unsigned short sBl[256 * 32];

    const int tid  = threadIdx.x;
    const int lane = tid & 63;
    const int wave = tid >> 6;
    const int l16  = lane & 15;
    const int quad = lane >> 4;
    const long m0  = (long)blockIdx.x * 64;
    const int  n0  = wave * 64;

    f4_t acc[4][4];
#pragma unroll
    for (int mt = 0; mt < 4; ++mt)
#pragma unroll
        for (int nt = 0; nt < 4; ++nt) acc[mt][nt] = (f4_t){0.f, 0.f, 0.f, 0.f};

    long asr = m0 + wave * 16 + (lane >> 2);
    if (asr >= M) asr = M - 1;  // clamp: garbage rows never stored
    const unsigned short* gAh = Ahi + asr * Kp + (lane & 3) * 8;
    const unsigned short* gAl = Alo + asr * Kp + (lane & 3) * 8;
    unsigned short* lAh = &sAh[wave * 512];
    unsigned short* lAl = &sAl[wave * 512];
    const unsigned short* gBh[4];
    const unsigned short* gBl[4];
    unsigned short* lBh[4];
    unsigned short* lBl[4];
#pragma unroll
    for (int j = 0; j < 4; ++j) {
        long br = wave * 64 + j * 16 + (lane >> 2);
        gBh[j] = Bhi + br * Kp + (lane & 3) * 8;
        gBl[j] = Blo + br * Kp + (lane & 3) * 8;
        lBh[j] = &sBh[wave * 2048 + j * 512];
        lBl[j] = &sBl[wave * 2048 + j * 512];
    }

    for (int k0 = 0; k0 < Kp; k0 += 32) {
        async_cp16(gAh + k0, lAh);
        async_cp16(gAl + k0, lAl);
#pragma unroll
        for (int j = 0; j < 4; ++j) {
            async_cp16(gBh[j] + k0, lBh[j]);
            async_cp16(gBl[j] + k0, lBl[j]);
        }
        __syncthreads();

        bf8_t ah[4], al[4];
#pragma unroll
        for (int mt = 0; mt < 4; ++mt) {
            ah[mt] = *(const bf8_t*)&sAh[(mt * 16 + l16) * 32 + quad * 8];
            al[mt] = *(const bf8_t*)&sAl[(mt * 16 + l16) * 32 + quad * 8];
        }
#pragma unroll
        for (int nt = 0; nt < 4; ++nt) {
            bf8_t bh = *(const bf8_t*)&sBh[(n0 + nt * 16 + l16) * 32 + quad * 8];
            bf8_t bl = *(const bf8_t*)&sBl[(n0 + nt * 16 + l16) * 32 + quad * 8];
#pragma unroll
            for (int mt = 0; mt < 4; ++mt) {
                acc[mt][nt] = __builtin_amdgcn_mfma_f32_16x16x32_bf16(ah[mt], bh, acc[mt][nt], 0, 0, 0);
                acc[mt][nt] = __builtin_amdgcn_mfma_f32_16x16x32_bf16(al[mt], bh, acc[mt][nt], 0, 0, 0);
                acc[mt][nt] = __builtin_amdgcn_mfma_f32_16x16x32_bf16(ah[mt], bl, acc[mt][nt], 0, 0, 0);
            }
        }
        __syncthreads();
    }

    const bool left = (n0 < 128);
    float* __restrict__ Cb = left ? C0 : C1;
    float badd[4];
    int   ncol[4];
#pragma unroll
    for (int nt = 0; nt < 4; ++nt) {
        int ng = n0 + nt * 16 + l16;
        ncol[nt] = left ? ng : (ng - 128);
        badd[nt] = left ? 0.f : bias[ng - 128];
    }
#pragma unroll
    for (int mt = 0; mt < 4; ++mt) {
#pragma unroll
        for (int r = 0; r < 4; ++r) {
            long row = m0 + mt * 16 + quad * 4 + r;
            if (row < M) {
#pragma unroll
                for (int nt = 0; nt < 4; ++nt)
                    Cb[row * 128 + ncol[nt]] = acc[mt][nt][r] + badd[nt];
            }
        }
    }
}

// ---------------------------------------------------------------------------
// CSR gather: out[n] += invdeg[n] * sum_{j in adj(n)} Pl[csr_src[j]]
// 32 lanes/node (float4/lane), 8 nodes/block, 8+4 edge unroll for MLP.
// ---------------------------------------------------------------------------
__global__ __launch_bounds__(256) void gather_agg(const float* __restrict__ Pl,
                                                  const int* __restrict__ row_start,
                                                  const int* __restrict__ csr_src,
                                                  const float* __restrict__ invdeg,
                                                  float* __restrict__ out) {
    int slot = threadIdx.x >> 5;
    int lane = threadIdx.x & 31;
    int node = blockIdx.x * 8 + slot;
    if (node >= N_NODES) return;
    int beg = row_start[node];
    int end = row_start[node + 1];
    const float* base = Pl + lane * 4;
    float sx = 0.f, sy = 0.f, sz = 0.f, sw = 0.f;
    int j = beg;
    for (; j + 8 <= end; j += 8) {
        int idx[8];
#pragma unroll
        for (int u = 0; u < 8; ++u) idx[u] = csr_src[j + u];
        float4 v[8];
#pragma unroll
        for (int u = 0; u < 8; ++u) v[u] = *(const float4*)(base + (long)idx[u] * HID);
#pragma unroll
        for (int u = 0; u < 8; ++u) {
            sx += v[u].x; sy += v[u].y; sz += v[u].z; sw += v[u].w;
        }
    }
    if (j + 4 <= end) {
        int idx[4];
#pragma unroll
        for (int u = 0; u < 4; ++u) idx[u] = csr_src[j + u];
        float4 v[4];
#pragma unroll
        for (int u = 0; u < 4; ++u) v[u] = *(const float4*)(base + (long)idx[u] * HID);
#pragma unroll
        for (int u = 0; u < 4; ++u) {
            sx += v[u].x; sy += v[u].y; sz += v[u].z; sw += v[u].w;
        }
        j += 4;
    }
    for (; j < end; ++j) {
        int i0 = csr_src[j];
        float4 v0 = *(const float4*)(base + (long)i0 * HID);
        sx += v0.x; sy += v0.y; sz += v0.z; sw += v0.w;
    }
    float w = invdeg[node];
    float* o = out + (long)node * HID + lane * 4;
    float4 cur = *(float4*)o;
    cur.x += sx * w;
    cur.y += sy * w;
    cur.z += sz * w;
    cur.w += sw * w;
    *(float4*)o = cur;
}

// ---------------------------------------------------------------------------
// BatchNorm: stats -> finalize -> apply(+ReLU)
// ---------------------------------------------------------------------------
__global__ __launch_bounds__(256) void bn_stats(const float* __restrict__ h,
                                                float* __restrict__ sums) {
    int c    = threadIdx.x & 127;
    int half = threadIdx.x >> 7;
    float s = 0.f, s2 = 0.f;
    for (int r = blockIdx.x * 2 + half; r < N_NODES; r += gridDim.x * 2) {
        float v = h[(long)r * HID + c];
        s  += v;
        s2 += v * v;
    }
    atomicAdd(&sums[c], s);
    atomicAdd(&sums[HID + c], s2);
}

__global__ __launch_bounds__(128) void bn_finalize(const float* __restrict__ sums,
                                                   const float* __restrict__ gamma,
                                                   const float* __restrict__ beta,
                                                   float* __restrict__ ss) {
    int c = threadIdx.x;
    const float invn = 1.0f / (float)N_NODES;
    float mu  = sums[c] * invn;
    float var = sums[HID + c] * invn - mu * mu;
    float sc  = gamma[c] * rsqrtf(var + BN_EPS);
    ss[c]       = sc;
    ss[HID + c] = beta[c] - mu * sc;
}

__global__ __launch_bounds__(256) void bn_apply_relu(float* __restrict__ h,
                                                     const float* __restrict__ ss,
                                                     unsigned short* __restrict__ Hhi,
                                                     unsigned short* __restrict__ Hlo) {
    long i = (long)blockIdx.x * 256 + threadIdx.x;
    if (i >= (long)N_NODES * 32) return;
    int c4 = (int)(i & 31) * 4;
    float4 v  = *(float4*)&h[i * 4];
    float4 sc = *(const float4*)&ss[c4];
    float4 sh = *(const float4*)&ss[HID + c4];
    v.x = fmaxf(v.x * sc.x + sh.x, 0.f);
    v.y = fmaxf(v.y * sc.y + sh.y, 0.f);
    v.z = fmaxf(v.z * sc.z + sh.z, 0.f);
    v.w = fmaxf(v.w * sc.w + sh.w, 0.f);
    if (Hhi) {
        ushort4 hh, ll;
        hh.x = f2bf(v.x); ll.x = f2bf(v.x - bf2f(hh.x));
        hh.y = f2bf(v.y); ll.y = f2bf(v.y - bf2f(hh.y));
        hh.z = f2bf(v.z); ll.z = f2bf(v.z - bf2f(hh.z));
        hh.w = f2bf(v.w); ll.w = f2bf(v.w - bf2f(hh.w));
        *(ushort4*)&Hhi[i * 4] = hh;
        *(ushort4*)&Hlo[i * 4] = ll;
    } else {
        *(float4*)&h[i * 4] = v;
    }
}

// ---------------------------------------------------------------------------
// global mean pool
// ---------------------------------------------------------------------------
#define POOL_ROWS 128
__global__ __launch_bounds__(128) void pool_kernel(const float* __restrict__ h,
                                                   const int* __restrict__ batch,
                                                   float* __restrict__ pooled,
                                                   float* __restrict__ cnt) {
    int c  = threadIdx.x;
    int r0 = blockIdx.x * POOL_ROWS;
    if (r0 >= N_NODES) return;
    int r1 = min(r0 + POOL_ROWS, N_NODES);
    int cur = batch[r0];
    float acc = 0.f, n = 0.f;
    for (int r = r0; r < r1; ++r) {
        int b = batch[r];
        if (b != cur) {
            atomicAdd(&pooled[cur * HID + c], acc);
            if (c == 0) atomicAdd(&cnt[cur], n);
            acc = 0.f;
            n   = 0.f;
            cur = b;
        }
        acc += h[(long)r * HID + c];
        n   += 1.f;
    }
    atomicAdd(&pooled[cur * HID + c], acc);
    if (c == 0) atomicAdd(&cnt[cur], n);
}

// ---------------------------------------------------------------------------
// head
// ---------------------------------------------------------------------------
__global__ __launch_bounds__(128) void head_kernel(const float* __restrict__ pooled,
                                                   const float* __restrict__ cnt,
                                                   const float* __restrict__ Wc,
                                                   const float* __restrict__ bc,
                                                   float* __restrict__ out) {
    int g = threadIdx.x;
    float inv = 1.0f / fmaxf(cnt[g], 1.0f);
    float o0 = bc[0], o1 = bc[1];
    for (int c = 0; c < HID; ++c) {
        float v = pooled[g * HID + c] * inv;
        out[N_GRAPHS * N_CLASSES + g * HID + c] = v;
        o0 += v * Wc[c * 2 + 0];
        o1 += v * Wc[c * 2 + 1];
    }
    out[g * 2 + 0] = o0;
    out[g * 2 + 1] = o1;
}

// ---------------------------------------------------------------------------
// launch
// ---------------------------------------------------------------------------
extern "C" void kernel_launch(void* const* d_in, const int* in_sizes, int n_in,
                              void* d_out, int out_size, void* d_ws, size_t ws_size,
                              hipStream_t stream) {
    const float* x     = (const float*)d_in[0];
    const int*   ei    = (const int*)d_in[1];
    const int*   batch = (const int*)d_in[2];
    const float* W1l = (const float*)d_in[3];
    const float* W1r = (const float*)d_in[4];
    const float* b1  = (const float*)d_in[5];
    const float* g1  = (const float*)d_in[6];
    const float* be1 = (const float*)d_in[7];
    const float* W2l = (const float*)d_in[8];
    const float* W2r = (const float*)d_in[9];
    const float* b2  = (const float*)d_in[10];
    const float* g2  = (const float*)d_in[11];
    const float* be2 = (const float*)d_in[12];
    const float* W3l = (const float*)d_in[13];
    const float* W3r = (const float*)d_in[14];
    const float* b3  = (const float*)d_in[15];
    const float* g3  = (const float*)d_in[16];
    const float* be3 = (const float*)d_in[17];
    const float* Wc  = (const float*)d_in[18];
    const float* bc  = (const float*)d_in[19];

    const int* src = ei;
    const int* dst = ei + N_EDGES;

    float* ws = (float*)d_ws;
    const long FEAT = (long)N_NODES * HID;
    float* buf0 = ws;
    float* buf1 = ws + FEAT;
    float* buf2 = ws + 2 * FEAT;
    int*   ideg      = (int*)(ws + 3 * FEAT);        // 50000
    int*   row_start = ideg + N_NODES;               // 50001 (pad to 50004)
    int*   cursor    = row_start + N_NODES + 4;      // 50000
    int*   csr_src   = cursor + N_NODES;             // 600000
    int*   bsum      = csr_src + N_EDGES;            // 128
    float* invdeg    = (float*)(bsum + 128);         // 50000
    float* sums      = invdeg + N_NODES;             // 3 * 256
    float* ss        = sums + 3 * 2 * HID;           // 256
    float* pooled    = ss + 2 * HID;                 // 16384
    float* cnt       = pooled + N_GRAPHS * HID;      // 128
    unsigned short* Bhi  = (unsigned short*)(cnt + N_GRAPHS);  // 256*320
    unsigned short* Blo  = Bhi + 256 * KP1;                    // 256*320
    unsigned short* Axhi = Blo + 256 * KP1;                    // 50000*320
    unsigned short* Axlo = Axhi + (long)N_NODES * KP1;         // 50000*320
    unsigned short* Hhi  = Axlo + (long)N_NODES * KP1;         // 50000*128
    unsigned short* Hlo  = Hhi + FEAT;                         // 50000*128

    float* outp = (float*)d_out;

    const int gemm_grid   = (N_NODES + 63) / 64;     // 782
    const int gather_grid = (N_NODES + 7) / 8;
    const int apply_grid  = (int)(((long)N_NODES * 32 + 255) / 256);
    const int pool_grid   = (N_NODES + POOL_ROWS - 1) / POOL_ROWS;
    const int prepx_grid  = (N_NODES * (KP1 / 4) + 255) / 256;

    // --- CSR build (once per call) ---
    hipMemsetAsync(ideg, 0, N_NODES * sizeof(int), stream);
    hipMemsetAsync(cursor, 0, N_NODES * sizeof(int), stream);
    hipMemsetAsync(sums, 0, 3 * 2 * HID * sizeof(float), stream);
    deg_kernel<<<(N_EDGES + 255) / 256, 256, 0, stream>>>(dst, ideg);
    scan_p1<<<NB, 256, 0, stream>>>(ideg, bsum);
    scan_p2<<<1, 128, 0, stream>>>(bsum, row_start);
    scan_p3<<<NB, 256, 0, stream>>>(ideg, bsum, row_start, invdeg);
    fill_kernel<<<(N_EDGES + 255) / 256, 256, 0, stream>>>(src, dst, row_start, cursor, csr_src);

    // --- split x (A operand for layer 1) ---
    prep_x<<<prepx_grid, 256, 0, stream>>>(x, Axhi, Axlo);

    // ---------------- layer 1 (A=x split, Kp=320) ----------------
    prep_w<<<(256 * KP1 + 255) / 256, 256, 0, stream>>>(W1l, W1r, IN_CH, KP1, Bhi, Blo);
    gemm_mfma<<<gemm_grid, 256, 0, stream>>>(Axhi, Axlo, N_NODES, KP1, Bhi, Blo, b1, buf0, buf1);
    gather_agg<<<gather_grid, 256, 0, stream>>>(buf0, row_start, csr_src, invdeg, buf1);
    bn_stats<<<256, 256, 0, stream>>>(buf1, sums);
    bn_finalize<<<1, 128, 0, stream>>>(sums, g1, be1, ss);
    bn_apply_relu<<<apply_grid, 256, 0, stream>>>(buf1, ss, Hhi, Hlo);

    // ---------------- layer 2 (A=h1 split, Kp=128) ----------------
    prep_w<<<(256 * HID + 255) / 256, 256, 0, stream>>>(W2l, W2r, HID, HID, Bhi, Blo);
    gemm_mfma<<<gemm_grid, 256, 0, stream>>>(Hhi, Hlo, N_NODES, HID, Bhi, Blo, b2, buf0, buf2);
    gather_agg<<<gather_grid, 256, 0, stream>>>(buf0, row_start, csr_src, invdeg, buf2);
    bn_stats<<<256, 256, 0, stream>>>(buf2, sums + 256);
    bn_finalize<<<1, 128, 0, stream>>>(sums + 256, g2, be2, ss);
    bn_apply_relu<<<apply_grid, 256, 0, stream>>>(buf2, ss, Hhi, Hlo);

    // ---------------- layer 3 (A=h2 split, Kp=128) ----------------
    prep_w<<<(256 * HID + 255) / 256, 256, 0, stream>>>(W3l, W3r, HID, HID, Bhi, Blo);
    gemm_mfma<<<gemm_grid, 256, 0, stream>>>(Hhi, Hlo, N_NODES, HID, Bhi, Blo, b3, buf0, buf1);
    gather_agg<<<gather_grid, 256, 0, stream>>>(buf0, row_start, csr_src, invdeg, buf1);
    bn_stats<<<256, 256, 0, stream>>>(buf1, sums + 512);
    bn_finalize<<<1, 128, 0, stream>>>(sums + 512, g3, be3, ss);
    bn_apply_relu<<<apply_grid, 256, 0, stream>>>(buf1, ss, nullptr, nullptr);  // fp32 in place

    // ---------------- pool + head ----------------
    hipMemsetAsync(pooled, 0, (N_GRAPHS * HID + N_GRAPHS) * sizeof(float), stream);
    pool_kernel<<<pool_grid, 128, 0, stream>>>(buf1, batch, pooled, cnt);
    head_kernel<<<1, 128, 0, stream>>>(pooled, cnt, Wc, bc, outp);
}

// Round 7
// 659.690 us; speedup vs baseline: 1.1932x; 1.0112x over previous
//
#include <hip/hip_runtime.h>

#define N_NODES   50000
#define N_EDGES   600000
#define IN_CH     300
#define HID       128
#define N_CLASSES 2
#define N_GRAPHS  128
#define BN_EPS    1e-5f

#define NB ((N_NODES + 511) / 512)   // scan blocks = 98
#define KP1 320

typedef __attribute__((ext_vector_type(8))) short bf8_t;   // 8 bf16 (4 VGPRs)
typedef __attribute__((ext_vector_type(4))) float f4_t;    // MFMA acc

// bf16 round-to-nearest-even helpers
__device__ __forceinline__ unsigned short f2bf(float x) {
    union { float f; unsigned u; } q; q.f = x;
    unsigned r = q.u + 0x7fffu + ((q.u >> 16) & 1u);
    return (unsigned short)(r >> 16);
}
__device__ __forceinline__ float bf2f(unsigned short h) {
    union { float f; unsigned u; } q; q.u = ((unsigned)h) << 16; return q.f;
}

// async global->LDS 16B copy: LDS dest = wave-uniform base + lane*16
__device__ __forceinline__ void async_cp16(const void* g, void* l) {
    __builtin_amdgcn_global_load_lds(
        (const __attribute__((address_space(1))) unsigned int*)g,
        (__attribute__((address_space(3))) unsigned int*)l, 16, 0, 0);
}

// ---------------------------------------------------------------------------
// degree count
// ---------------------------------------------------------------------------
__global__ __launch_bounds__(256) void deg_kernel(const int* __restrict__ dst,
                                                  int* __restrict__ ideg) {
    int e = blockIdx.x * 256 + threadIdx.x;
    if (e < N_EDGES) atomicAdd(&ideg[dst[e]], 1);
}

// ---------------------------------------------------------------------------
// 3-phase exclusive scan of ideg -> row_start (+ invdeg fused in phase 3)
// ---------------------------------------------------------------------------
__global__ __launch_bounds__(256) void scan_p1(const int* __restrict__ ideg,
                                               int* __restrict__ bsum) {
    int b = blockIdx.x, t = threadIdx.x;
    int i0 = b * 512 + t * 2;
    int s = 0;
    if (i0 < N_NODES) {
        int2 v = *(const int2*)&ideg[i0];
        s = v.x + v.y;
    }
#pragma unroll
    for (int d = 1; d < 64; d <<= 1) s += __shfl_down(s, d);
    __shared__ int ws[4];
    int lane = t & 63, wv = t >> 6;
    if (lane == 0) ws[wv] = s;
    __syncthreads();
    if (t == 0) bsum[b] = ws[0] + ws[1] + ws[2] + ws[3];
}

__global__ __launch_bounds__(128) void scan_p2(int* __restrict__ bsum,
                                               int* __restrict__ row_start) {
    __shared__ int sh[128];
    int t = threadIdx.x;
    int v = (t < NB) ? bsum[t] : 0;
    sh[t] = v;
    __syncthreads();
#pragma unroll
    for (int off = 1; off < 128; off <<= 1) {
        int u = (t >= off) ? sh[t - off] : 0;
        __syncthreads();
        sh[t] += u;
        __syncthreads();
    }
    if (t < NB) bsum[t] = sh[t] - v;          // exclusive
    if (t == NB - 1) row_start[N_NODES] = sh[t];
}

__global__ __launch_bounds__(256) void scan_p3(const int* __restrict__ ideg,
                                               const int* __restrict__ bsum,
                                               int* __restrict__ row_start,
                                               float* __restrict__ invdeg) {
    int b = blockIdx.x, t = threadIdx.x;
    int lane = t & 63, wv = t >> 6;
    int i0 = b * 512 + t * 2;
    int v0 = 0, v1 = 0;
    if (i0 < N_NODES) {
        int2 v = *(const int2*)&ideg[i0];
        v0 = v.x; v1 = v.y;
    }
    int tot = v0 + v1;
    int s = tot;
#pragma unroll
    for (int d = 1; d < 64; d <<= 1) {
        int u = __shfl_up(s, d);
        if (lane >= d) s += u;
    }
    __shared__ int ws[4];
    if (lane == 63) ws[wv] = s;
    __syncthreads();
    int woff = 0;
    for (int w = 0; w < wv; ++w) woff += ws[w];
    int base = bsum[b] + woff + (s - tot);
    if (i0 < N_NODES) {
        row_start[i0]     = base;
        row_start[i0 + 1] = base + v0;
        invdeg[i0]     = 1.0f / fmaxf((float)v0, 1.0f);
        invdeg[i0 + 1] = 1.0f / fmaxf((float)v1, 1.0f);
    }
}

__global__ __launch_bounds__(256) void fill_kernel(const int* __restrict__ src,
                                                   const int* __restrict__ dst,
                                                   const int* __restrict__ row_start,
                                                   int* __restrict__ cursor,
                                                   int* __restrict__ csr_src) {
    int e = blockIdx.x * 256 + threadIdx.x;
    if (e >= N_EDGES) return;
    int d = dst[e];
    int pos = row_start[d] + atomicAdd(&cursor[d], 1);
    csr_src[pos] = src[e];
}

// ---------------------------------------------------------------------------
// x -> split bf16 hi/lo planes (M x 320, zero-padded cols 300..319)
// ---------------------------------------------------------------------------
__global__ __launch_bounds__(256) void prep_x(const float* __restrict__ x,
                                              unsigned short* __restrict__ Ahi,
                                              unsigned short* __restrict__ Alo) {
    int idx = blockIdx.x * 256 + threadIdx.x;  // over N_NODES * 80
    if (idx >= N_NODES * (KP1 / 4)) return;
    int row = idx / (KP1 / 4);
    int c4  = (idx - row * (KP1 / 4)) * 4;
    float4 v = make_float4(0.f, 0.f, 0.f, 0.f);
    if (c4 < IN_CH) v = *(const float4*)&x[(long)row * IN_CH + c4];
    ushort4 h, l;
    h.x = f2bf(v.x); l.x = f2bf(v.x - bf2f(h.x));
    h.y = f2bf(v.y); l.y = f2bf(v.y - bf2f(h.y));
    h.z = f2bf(v.z); l.z = f2bf(v.z - bf2f(h.z));
    h.w = f2bf(v.w); l.w = f2bf(v.w - bf2f(h.w));
    *(ushort4*)&Ahi[(long)row * KP1 + c4] = h;
    *(ushort4*)&Alo[(long)row * KP1 + c4] = l;
}

// ---------------------------------------------------------------------------
// weight prep for ALL layers: BT[n][k] (256 x Kp, bf16 hi/lo, zero-pad k>=K)
// blockIdx.y = layer (0: Kp=320, 1/2: Kp=128)
// ---------------------------------------------------------------------------
__global__ __launch_bounds__(256) void prep_w_all(const float* __restrict__ W1l,
                                                  const float* __restrict__ W1r,
                                                  const float* __restrict__ W2l,
                                                  const float* __restrict__ W2r,
                                                  const float* __restrict__ W3l,
                                                  const float* __restrict__ W3r,
                                                  unsigned short* __restrict__ B1h,
                                                  unsigned short* __restrict__ B1l,
                                                  unsigned short* __restrict__ B2h,
                                                  unsigned short* __restrict__ B2l,
                                                  unsigned short* __restrict__ B3h,
                                                  unsigned short* __restrict__ B3l) {
    int layer = blockIdx.y;
    int Kp = (layer == 0) ? KP1 : HID;
    int K  = (layer == 0) ? IN_CH : HID;
    const float* Wl = (layer == 0) ? W1l : ((layer == 1) ? W2l : W3l);
    const float* Wr = (layer == 0) ? W1r : ((layer == 1) ? W2r : W3r);
    unsigned short* Bh = (layer == 0) ? B1h : ((layer == 1) ? B2h : B3h);
    unsigned short* Bl = (layer == 0) ? B1l : ((layer == 1) ? B2l : B3l);
    int idx = blockIdx.x * 256 + threadIdx.x;
    if (idx >= 256 * Kp) return;
    int n = idx / Kp;
    int k = idx - n * Kp;
    float v = 0.f;
    if (k < K) v = (n < 128) ? Wl[k * 128 + n] : Wr[k * 128 + (n - 128)];
    unsigned short h = f2bf(v);
    unsigned short l = f2bf(v - bf2f(h));
    Bh[idx] = h;
    Bl[idx] = l;
}

// ---------------------------------------------------------------------------
// split-bf16 MFMA GEMM, pipelined K-loop:
//   C0 = A@Wl , C1 = A@Wr + bias   (N = 128+128)
// block tile 64(M) x 256(N), 4 waves, wave tile 64x64 = 4x4 MFMA 16x16x32.
// A (HBM, high latency): double-buffered LDS, prefetched to overlap compute.
// B (L2-resident): single-buffered LDS, cheap drain per step.
// LDS = 2*8 + 32 = 48 KB -> 3 blocks/CU.
// ---------------------------------------------------------------------------
__global__ __launch_bounds__(256) void gemm_mfma(const unsigned short* __restrict__ Ahi,
                                                 const unsigned short* __restrict__ Alo,
                                                 int M, int Kp,
                                                 const unsigned short* __restrict__ Bhi,
                                                 const unsigned short* __restrict__ Blo,
                                                 const float* __restrict__ bias,
                                                 float* __restrict__ C0,
                                                 float* __restrict__ C1) {
    __shared__ __align__(16) unsigned short sAh[2][64 * 32];
    __shared__ __align__(16) unsigned short sAl[2][64 * 32];
    __shared__ __align__(16) unsigned short sBh[256 * 32];
    __shared__ __align__(16) unsigned short sBl[256 * 32];

    const int tid  = threadIdx.x;
    const int lane = tid & 63;
    const int wave = tid >> 6;
    const int l16  = lane & 15;
    const int quad = lane >> 4;
    const long m0  = (long)blockIdx.x * 64;
    const int  n0  = wave * 64;

    f4_t acc[4][4];
#pragma unroll
    for (int mt = 0; mt < 4; ++mt)
#pragma unroll
        for (int nt = 0; nt < 4; ++nt) acc[mt][nt] = (f4_t){0.f, 0.f, 0.f, 0.f};

    // A staging: wave w stages rows m0 + w*16 + lane/4, ushort col (lane&3)*8
    long asr = m0 + wave * 16 + (lane >> 2);
    if (asr >= M) asr = M - 1;  // clamp: garbage rows never stored
    const unsigned short* gAh = Ahi + asr * Kp + (lane & 3) * 8;
    const unsigned short* gAl = Alo + asr * Kp + (lane & 3) * 8;
    // B staging: wave w iter j stages rows w*64 + j*16 + lane/4
    const unsigned short* gBh[4];
    const unsigned short* gBl[4];
    unsigned short* lBh[4];
    unsigned short* lBl[4];
#pragma unroll
    for (int j = 0; j < 4; ++j) {
        long br = wave * 64 + j * 16 + (lane >> 2);
        gBh[j] = Bhi + br * Kp + (lane & 3) * 8;
        gBl[j] = Blo + br * Kp + (lane & 3) * 8;
        lBh[j] = &sBh[wave * 2048 + j * 512];
        lBl[j] = &sBl[wave * 2048 + j * 512];
    }

    const int nsteps = Kp >> 5;

    // prefetch A(0) into buffer 0
    async_cp16(gAh, &sAh[0][wave * 512]);
    async_cp16(gAl, &sAl[0][wave * 512]);

    for (int step = 0; step < nsteps; ++step) {
        const int k0 = step << 5;
        const int cb = step & 1;

        __syncthreads();   // B buf free (prev compute done) + A(step) arrived

        // stage B(step) into the single B buffer
#pragma unroll
        for (int j = 0; j < 4; ++j) {
            async_cp16(gBh[j] + k0, lBh[j]);
            async_cp16(gBl[j] + k0, lBl[j]);
        }
        __syncthreads();   // drain B(step) (L2, cheap); nothing else outstanding

        // prefetch A(step+1) -> other buffer; overlaps the whole compute phase
        if (step + 1 < nsteps) {
            async_cp16(gAh + k0 + 32, &sAh[cb ^ 1][wave * 512]);
            async_cp16(gAl + k0 + 32, &sAl[cb ^ 1][wave * 512]);
        }

        // compute from sA*[cb] and sB*
        bf8_t ah[4], al[4];
#pragma unroll
        for (int mt = 0; mt < 4; ++mt) {
            ah[mt] = *(const bf8_t*)&sAh[cb][(mt * 16 + l16) * 32 + quad * 8];
            al[mt] = *(const bf8_t*)&sAl[cb][(mt * 16 + l16) * 32 + quad * 8];
        }
#pragma unroll
        for (int nt = 0; nt < 4; ++nt) {
            bf8_t bh = *(const bf8_t*)&sBh[(n0 + nt * 16 + l16) * 32 + quad * 8];
            bf8_t bl = *(const bf8_t*)&sBl[(n0 + nt * 16 + l16) * 32 + quad * 8];
#pragma unroll
            for (int mt = 0; mt < 4; ++mt) {
                acc[mt][nt] = __builtin_amdgcn_mfma_f32_16x16x32_bf16(ah[mt], bh, acc[mt][nt], 0, 0, 0);
                acc[mt][nt] = __builtin_amdgcn_mfma_f32_16x16x32_bf16(al[mt], bh, acc[mt][nt], 0, 0, 0);
                acc[mt][nt] = __builtin_amdgcn_mfma_f32_16x16x32_bf16(ah[mt], bl, acc[mt][nt], 0, 0, 0);
            }
        }
    }

    // epilogue: wave-uniform half selection (n0<128 -> C0, else C1 + bias)
    const bool left = (n0 < 128);
    float* __restrict__ Cb = left ? C0 : C1;
    float badd[4];
    int   ncol[4];
#pragma unroll
    for (int nt = 0; nt < 4; ++nt) {
        int ng = n0 + nt * 16 + l16;
        ncol[nt] = left ? ng : (ng - 128);
        badd[nt] = left ? 0.f : bias[ng - 128];
    }
#pragma unroll
    for (int mt = 0; mt < 4; ++mt) {
#pragma unroll
        for (int r = 0; r < 4; ++r) {
            long row = m0 + mt * 16 + quad * 4 + r;
            if (row < M) {
#pragma unroll
                for (int nt = 0; nt < 4; ++nt)
                    Cb[row * 128 + ncol[nt]] = acc[mt][nt][r] + badd[nt];
            }
        }
    }
}

// ---------------------------------------------------------------------------
// CSR gather: out[n] += invdeg[n] * sum_{j in adj(n)} Pl[csr_src[j]]
// 32 lanes/node (float4/lane), 8 nodes/block, 8+4 edge unroll for MLP.
// ---------------------------------------------------------------------------
__global__ __launch_bounds__(256) void gather_agg(const float* __restrict__ Pl,
                                                  const int* __restrict__ row_start,
                                                  const int* __restrict__ csr_src,
                                                  const float* __restrict__ invdeg,
                                                  float* __restrict__ out) {
    int slot = threadIdx.x >> 5;
    int lane = threadIdx.x & 31;
    int node = blockIdx.x * 8 + slot;
    if (node >= N_NODES) return;
    int beg = row_start[node];
    int end = row_start[node + 1];
    const float* base = Pl + lane * 4;
    float sx = 0.f, sy = 0.f, sz = 0.f, sw = 0.f;
    int j = beg;
    for (; j + 8 <= end; j += 8) {
        int idx[8];
#pragma unroll
        for (int u = 0; u < 8; ++u) idx[u] = csr_src[j + u];
        float4 v[8];
#pragma unroll
        for (int u = 0; u < 8; ++u) v[u] = *(const float4*)(base + (long)idx[u] * HID);
#pragma unroll
        for (int u = 0; u < 8; ++u) {
            sx += v[u].x; sy += v[u].y; sz += v[u].z; sw += v[u].w;
        }
    }
    if (j + 4 <= end) {
        int idx[4];
#pragma unroll
        for (int u = 0; u < 4; ++u) idx[u] = csr_src[j + u];
        float4 v[4];
#pragma unroll
        for (int u = 0; u < 4; ++u) v[u] = *(const float4*)(base + (long)idx[u] * HID);
#pragma unroll
        for (int u = 0; u < 4; ++u) {
            sx += v[u].x; sy += v[u].y; sz += v[u].z; sw += v[u].w;
        }
        j += 4;
    }
    for (; j < end; ++j) {
        int i0 = csr_src[j];
        float4 v0 = *(const float4*)(base + (long)i0 * HID);
        sx += v0.x; sy += v0.y; sz += v0.z; sw += v0.w;
    }
    float w = invdeg[node];
    float* o = out + (long)node * HID + lane * 4;
    float4 cur = *(float4*)o;
    cur.x += sx * w;
    cur.y += sy * w;
    cur.z += sz * w;
    cur.w += sw * w;
    *(float4*)o = cur;
}

// ---------------------------------------------------------------------------
// BatchNorm: stats -> apply(+ReLU, finalize fused)
// ---------------------------------------------------------------------------
__global__ __launch_bounds__(256) void bn_stats(const float* __restrict__ h,
                                                float* __restrict__ sums) {
    int c    = threadIdx.x & 127;
    int half = threadIdx.x >> 7;
    float s = 0.f, s2 = 0.f;
    for (int r = blockIdx.x * 2 + half; r < N_NODES; r += gridDim.x * 2) {
        float v = h[(long)r * HID + c];
        s  += v;
        s2 += v * v;
    }
    atomicAdd(&sums[c], s);
    atomicAdd(&sums[HID + c], s2);
}

__global__ __launch_bounds__(256) void bn_apply_relu(float* __restrict__ h,
                                                     const float* __restrict__ sums,
                                                     const float* __restrict__ gamma,
                                                     const float* __restrict__ beta,
                                                     unsigned short* __restrict__ Hhi,
                                                     unsigned short* __restrict__ Hlo) {
    long i = (long)blockIdx.x * 256 + threadIdx.x;
    if (i >= (long)N_NODES * 32) return;
    int c4 = (int)(i & 31) * 4;
    const float invn = 1.0f / (float)N_NODES;
    float4 s  = *(const float4*)&sums[c4];
    float4 s2 = *(const float4*)&sums[HID + c4];
    float4 g  = *(const float4*)&gamma[c4];
    float4 be = *(const float4*)&beta[c4];
    float4 sc, sh;
    {
        float mu, var;
        mu = s.x * invn; var = s2.x * invn - mu * mu; sc.x = g.x * rsqrtf(var + BN_EPS); sh.x = be.x - mu * sc.x;
        mu = s.y * invn; var = s2.y * invn - mu * mu; sc.y = g.y * rsqrtf(var + BN_EPS); sh.y = be.y - mu * sc.y;
        mu = s.z * invn; var = s2.z * invn - mu * mu; sc.z = g.z * rsqrtf(var + BN_EPS); sh.z = be.z - mu * sc.z;
        mu = s.w * invn; var = s2.w * invn - mu * mu; sc.w = g.w * rsqrtf(var + BN_EPS); sh.w = be.w - mu * sc.w;
    }
    float4 v = *(float4*)&h[i * 4];
    v.x = fmaxf(v.x * sc.x + sh.x, 0.f);
    v.y = fmaxf(v.y * sc.y + sh.y, 0.f);
    v.z = fmaxf(v.z * sc.z + sh.z, 0.f);
    v.w = fmaxf(v.w * sc.w + sh.w, 0.f);
    if (Hhi) {
        ushort4 hh, ll;
        hh.x = f2bf(v.x); ll.x = f2bf(v.x - bf2f(hh.x));
        hh.y = f2bf(v.y); ll.y = f2bf(v.y - bf2f(hh.y));
        hh.z = f2bf(v.z); ll.z = f2bf(v.z - bf2f(hh.z));
        hh.w = f2bf(v.w); ll.w = f2bf(v.w - bf2f(hh.w));
        *(ushort4*)&Hhi[i * 4] = hh;
        *(ushort4*)&Hlo[i * 4] = ll;
    } else {
        *(float4*)&h[i * 4] = v;
    }
}

// ---------------------------------------------------------------------------
// global mean pool
// ---------------------------------------------------------------------------
#define POOL_ROWS 128
__global__ __launch_bounds__(128) void pool_kernel(const float* __restrict__ h,
                                                   const int* __restrict__ batch,
                                                   float* __restrict__ pooled,
                                                   float* __restrict__ cnt) {
    int c  = threadIdx.x;
    int r0 = blockIdx.x * POOL_ROWS;
    if (r0 >= N_NODES) return;
    int r1 = min(r0 + POOL_ROWS, N_NODES);
    int cur = batch[r0];
    float acc = 0.f, n = 0.f;
    for (int r = r0; r < r1; ++r) {
        int b = batch[r];
        if (b != cur) {
            atomicAdd(&pooled[cur * HID + c], acc);
            if (c == 0) atomicAdd(&cnt[cur], n);
            acc = 0.f;
            n   = 0.f;
            cur = b;
        }
        acc += h[(long)r * HID + c];
        n   += 1.f;
    }
    atomicAdd(&pooled[cur * HID + c], acc);
    if (c == 0) atomicAdd(&cnt[cur], n);
}

// ---------------------------------------------------------------------------
// head
// ---------------------------------------------------------------------------
__global__ __launch_bounds__(128) void head_kernel(const float* __restrict__ pooled,
                                                   const float* __restrict__ cnt,
                                                   const float* __restrict__ Wc,
                                                   const float* __restrict__ bc,
                                                   float* __restrict__ out) {
    int g = threadIdx.x;
    float inv = 1.0f / fmaxf(cnt[g], 1.0f);
    float o0 = bc[0], o1 = bc[1];
    for (int c = 0; c < HID; ++c) {
        float v = pooled[g * HID + c] * inv;
        out[N_GRAPHS * N_CLASSES + g * HID + c] = v;
        o0 += v * Wc[c * 2 + 0];
        o1 += v * Wc[c * 2 + 1];
    }
    out[g * 2 + 0] = o0;
    out[g * 2 + 1] = o1;
}

// ---------------------------------------------------------------------------
// launch
// ---------------------------------------------------------------------------
extern "C" void kernel_launch(void* const* d_in, const int* in_sizes, int n_in,
                              void* d_out, int out_size, void* d_ws, size_t ws_size,
                              hipStream_t stream) {
    const float* x     = (const float*)d_in[0];
    const int*   ei    = (const int*)d_in[1];
    const int*   batch = (const int*)d_in[2];
    const float* W1l = (const float*)d_in[3];
    const float* W1r = (const float*)d_in[4];
    const float* b1  = (const float*)d_in[5];
    const float* g1  = (const float*)d_in[6];
    const float* be1 = (const float*)d_in[7];
    const float* W2l = (const float*)d_in[8];
    const float* W2r = (const float*)d_in[9];
    const float* b2  = (const float*)d_in[10];
    const float* g2  = (const float*)d_in[11];
    const float* be2 = (const float*)d_in[12];
    const float* W3l = (const float*)d_in[13];
    const float* W3r = (const float*)d_in[14];
    const float* b3  = (const float*)d_in[15];
    const float* g3  = (const float*)d_in[16];
    const float* be3 = (const float*)d_in[17];
    const float* Wc  = (const float*)d_in[18];
    const float* bc  = (const float*)d_in[19];

    const int* src = ei;
    const int* dst = ei + N_EDGES;

    float* ws = (float*)d_ws;
    const long FEAT = (long)N_NODES * HID;
    float* buf0 = ws;
    float* buf1 = ws + FEAT;
    float* buf2 = ws + 2 * FEAT;
    int*   ideg      = (int*)(ws + 3 * FEAT);        // 50000
    int*   cursor    = ideg + N_NODES;               // 50000 (adjacent to ideg for 1 memset)
    int*   row_start = cursor + N_NODES;             // 50001 (pad to 50004)
    int*   csr_src   = row_start + N_NODES + 4;      // 600000
    int*   bsum      = csr_src + N_EDGES;            // 128
    float* invdeg    = (float*)(bsum + 128);         // 50000
    float* sums      = invdeg + N_NODES;             // 3*256 (+pooled+cnt adjacent, 1 memset)
    float* pooled    = sums + 3 * 2 * HID;           // 16384
    float* cnt       = pooled + N_GRAPHS * HID;      // 128
    unsigned short* B1h  = (unsigned short*)(cnt + N_GRAPHS);  // 256*320
    unsigned short* B1l  = B1h + 256 * KP1;
    unsigned short* B2h  = B1l + 256 * KP1;                    // 256*128
    unsigned short* B2l  = B2h + 256 * HID;
    unsigned short* B3h  = B2l + 256 * HID;
    unsigned short* B3l  = B3h + 256 * HID;
    unsigned short* Axhi = B3l + 256 * HID;                    // 50000*320
    unsigned short* Axlo = Axhi + (long)N_NODES * KP1;
    unsigned short* Hhi  = Axlo + (long)N_NODES * KP1;         // 50000*128
    unsigned short* Hlo  = Hhi + FEAT;

    float* outp = (float*)d_out;

    const int gemm_grid   = (N_NODES + 63) / 64;     // 782
    const int gather_grid = (N_NODES + 7) / 8;
    const int apply_grid  = (int)(((long)N_NODES * 32 + 255) / 256);
    const int pool_grid   = (N_NODES + POOL_ROWS - 1) / POOL_ROWS;
    const int prepx_grid  = (N_NODES * (KP1 / 4) + 255) / 256;
    const dim3 prepw_grid((256 * KP1 + 255) / 256, 3);

    // --- zero scratch (2 merged memsets) ---
    hipMemsetAsync(ideg, 0, 2 * N_NODES * sizeof(int), stream);            // ideg + cursor
    hipMemsetAsync(sums, 0,
                   (3 * 2 * HID + N_GRAPHS * HID + N_GRAPHS) * sizeof(float), stream);

    // --- CSR build ---
    deg_kernel<<<(N_EDGES + 255) / 256, 256, 0, stream>>>(dst, ideg);
    scan_p1<<<NB, 256, 0, stream>>>(ideg, bsum);
    scan_p2<<<1, 128, 0, stream>>>(bsum, row_start);
    scan_p3<<<NB, 256, 0, stream>>>(ideg, bsum, row_start, invdeg);
    fill_kernel<<<(N_EDGES + 255) / 256, 256, 0, stream>>>(src, dst, row_start, cursor, csr_src);

    // --- operand prep ---
    prep_x<<<prepx_grid, 256, 0, stream>>>(x, Axhi, Axlo);
    prep_w_all<<<prepw_grid, 256, 0, stream>>>(W1l, W1r, W2l, W2r, W3l, W3r,
                                               B1h, B1l, B2h, B2l, B3h, B3l);

    // ---------------- layer 1 (A=x split, Kp=320) ----------------
    gemm_mfma<<<gemm_grid, 256, 0, stream>>>(Axhi, Axlo, N_NODES, KP1, B1h, B1l, b1, buf0, buf1);
    gather_agg<<<gather_grid, 256, 0, stream>>>(buf0, row_start, csr_src, invdeg, buf1);
    bn_stats<<<256, 256, 0, stream>>>(buf1, sums);
    bn_apply_relu<<<apply_grid, 256, 0, stream>>>(buf1, sums, g1, be1, Hhi, Hlo);

    // ---------------- layer 2 (A=h1 split, Kp=128) ----------------
    gemm_mfma<<<gemm_grid, 256, 0, stream>>>(Hhi, Hlo, N_NODES, HID, B2h, B2l, b2, buf0, buf2);
    gather_agg<<<gather_grid, 256, 0, stream>>>(buf0, row_start, csr_src, invdeg, buf2);
    bn_stats<<<256, 256, 0, stream>>>(buf2, sums + 256);
    bn_apply_relu<<<apply_grid, 256, 0, stream>>>(buf2, sums + 256, g2, be2, Hhi, Hlo);

    // ---------------- layer 3 (A=h2 split, Kp=128) ----------------
    gemm_mfma<<<gemm_grid, 256, 0, stream>>>(Hhi, Hlo, N_NODES, HID, B3h, B3l, b3, buf0, buf1);
    gather_agg<<<gather_grid, 256, 0, stream>>>(buf0, row_start, csr_src, invdeg, buf1);
    bn_stats<<<256, 256, 0, stream>>>(buf1, sums + 512);
    bn_apply_relu<<<apply_grid, 256, 0, stream>>>(buf1, sums + 512, g3, be3, nullptr, nullptr);

    // ---------------- pool + head ----------------
    pool_kernel<<<pool_grid, 128, 0, stream>>>(buf1, batch, pooled, cnt);
    head_kernel<<<1, 128, 0, stream>>>(pooled, cnt, Wc, bc, outp);
}